// Round 4
// baseline (775.073 us; speedup 1.0000x reference)
//
#include <hip/hip_runtime.h>

#define HID 128

typedef __attribute__((ext_vector_type(8))) short bf16x8;
typedef __attribute__((ext_vector_type(4))) float f32x4;

__device__ inline unsigned short f2bf(float f) {
    unsigned u = __float_as_uint(f);
    unsigned r = (u + 0x7FFF + ((u >> 16) & 1)) >> 16;   // RNE
    return (unsigned short)r;
}
__device__ inline float bf2f(unsigned short h) { return __uint_as_float((unsigned)h << 16); }

// ---------------- CSR build ----------------
__global__ void degree_kernel(const int* __restrict__ dst, int* __restrict__ deg, int E) {
    int e = blockIdx.x * blockDim.x + threadIdx.x;
    if (e < E) atomicAdd(&deg[dst[e]], 1);
}

__global__ void scan_reduce(const int* __restrict__ deg, int* __restrict__ bsum, int N) {
    __shared__ int sd[256];
    int b = blockIdx.x, t = threadIdx.x;
    int base = b * 1024, s = 0;
    for (int i = t; i < 1024; i += 256) {
        int idx = base + i;
        s += (idx < N) ? deg[idx] : 0;
    }
    sd[t] = s; __syncthreads();
    for (int st = 128; st > 0; st >>= 1) {
        if (t < st) sd[t] += sd[t + st];
        __syncthreads();
    }
    if (t == 0) bsum[b] = sd[0];
}

__global__ void scan_bsum(int* __restrict__ bsum, int nb) {
    __shared__ int s[256];
    int t = threadIdx.x;
    int v = (t < nb) ? bsum[t] : 0;
    s[t] = v; __syncthreads();
    for (int st = 1; st < 256; st <<= 1) {
        int add = (t >= st) ? s[t - st] : 0;
        __syncthreads();
        s[t] += add;
        __syncthreads();
    }
    if (t < nb) bsum[t] = s[t] - v;
}

__global__ void scan_final(const int* __restrict__ deg, const int* __restrict__ bsum,
                           int* __restrict__ off, int* __restrict__ pos, int N, int E) {
    __shared__ int ts[256];
    int b = blockIdx.x, t = threadIdx.x, base = b * 1024;
    int v[4], s = 0;
    #pragma unroll
    for (int j = 0; j < 4; ++j) {
        int idx = base + t * 4 + j;
        v[j] = (idx < N) ? deg[idx] : 0;
        s += v[j];
    }
    ts[t] = s; __syncthreads();
    int mine = s;
    for (int st = 1; st < 256; st <<= 1) {
        int add = (t >= st) ? ts[t - st] : 0;
        __syncthreads();
        ts[t] += add;
        __syncthreads();
    }
    int ex = ts[t] - mine + bsum[b];
    #pragma unroll
    for (int j = 0; j < 4; ++j) {
        int idx = base + t * 4 + j;
        if (idx < N) { off[idx] = ex; pos[idx] = ex; }
        ex += v[j];
    }
    if (b == 0 && t == 0) off[N] = E;
}

__global__ void bucket_kernel(const int* __restrict__ src, const int* __restrict__ dst,
                              int* __restrict__ pos, int* __restrict__ eid, int E) {
    int e = blockIdx.x * blockDim.x + threadIdx.x;
    if (e < E) {
        int p = atomicAdd(&pos[dst[e]], 1);
        eid[p] = src[e];
    }
}

// ---------------- gather aggregate (mean), one wave per node ----------------
template<int F>
__global__ __launch_bounds__(256) void aggregate_kernel(
    const float* __restrict__ feat, const int* __restrict__ eid,
    const int* __restrict__ off, float* __restrict__ agg, int N)
{
    int wave = threadIdx.x >> 6, lane = threadIdx.x & 63;
    int n = blockIdx.x * 4 + wave;
    if (n >= N) return;
    int s0 = __builtin_amdgcn_readfirstlane(off[n]);
    int s1 = __builtin_amdgcn_readfirstlane(off[n + 1]);

    if (F == 128) {
        float ax = 0.0f, ay = 0.0f;
        int i = s0;
        for (; i + 1 < s1; i += 2) {
            int sa = eid[i], sb = eid[i + 1];
            float2 va = *(const float2*)&feat[(size_t)sa * 128 + lane * 2];
            float2 vb = *(const float2*)&feat[(size_t)sb * 128 + lane * 2];
            ax += va.x + vb.x; ay += va.y + vb.y;
        }
        if (i < s1) {
            float2 va = *(const float2*)&feat[(size_t)eid[i] * 128 + lane * 2];
            ax += va.x; ay += va.y;
        }
        float inv = (s1 > s0) ? 1.0f / (float)(s1 - s0) : 0.0f;
        float2 r; r.x = ax * inv; r.y = ay * inv;
        *(float2*)&agg[(size_t)n * 128 + lane * 2] = r;
    } else {
        float a = 0.0f;
        int i = s0;
        for (; i + 1 < s1; i += 2) {
            int sa = eid[i], sb = eid[i + 1];
            a += feat[(size_t)sa * 64 + lane] + feat[(size_t)sb * 64 + lane];
        }
        if (i < s1) a += feat[(size_t)eid[i] * 64 + lane];
        float inv = (s1 > s0) ? 1.0f / (float)(s1 - s0) : 0.0f;
        agg[(size_t)n * 64 + lane] = a * inv;
    }
}

// ---------------- SAGE layer GEMM (fp32 VALU) ----------------
template<int K0, int K1, bool RELU>
__global__ __launch_bounds__(256) void layer_gemm(
    const float* __restrict__ agg, const float* __restrict__ xin,
    const float* __restrict__ Wl, const float* __restrict__ bl,
    const float* __restrict__ Wr,
    float* __restrict__ out, int N)
{
    __shared__ float As[64][33];
    __shared__ float Bs[32][128];

    const int t  = threadIdx.x;
    const int tm = t & 15, tn = t >> 4;
    const int n0 = blockIdx.x * 64;

    float acc[4][8] = {};

    for (int kc = 0; kc < K0 + K1; kc += 32) {
        const bool fromAgg = (kc < K0);
        const float* W = fromAgg ? (Wl + kc * HID) : (Wr + (kc - K0) * HID);
        for (int i = t; i < 32 * HID; i += 256)
            Bs[i >> 7][i & 127] = W[i];
        for (int i = t; i < 64 * 32; i += 256) {
            int m = i >> 5, j = i & 31;
            int n = n0 + m;
            float v = 0.0f;
            if (n < N) {
                if (fromAgg) v = agg[n * K0 + kc + j];
                else         v = xin[n * K1 + (kc - K0) + j];
            }
            As[m][j] = v;
        }
        __syncthreads();

        #pragma unroll 8
        for (int j = 0; j < 32; ++j) {
            float av[4];
            av[0] = As[tm * 4 + 0][j];
            av[1] = As[tm * 4 + 1][j];
            av[2] = As[tm * 4 + 2][j];
            av[3] = As[tm * 4 + 3][j];
            float4 b0 = *(const float4*)&Bs[j][tn * 4];
            float4 b1 = *(const float4*)&Bs[j][tn * 4 + 64];
            float bv[8] = {b0.x, b0.y, b0.z, b0.w, b1.x, b1.y, b1.z, b1.w};
            #pragma unroll
            for (int mi = 0; mi < 4; ++mi)
                #pragma unroll
                for (int ni = 0; ni < 8; ++ni)
                    acc[mi][ni] += av[mi] * bv[ni];
        }
        __syncthreads();
    }

    #pragma unroll
    for (int mi = 0; mi < 4; ++mi) {
        int n = n0 + tm * 4 + mi;
        if (n < N) {
            float4 v0, v1;
            float* p0 = (float*)&v0;
            float* p1 = (float*)&v1;
            #pragma unroll
            for (int ni = 0; ni < 4; ++ni) {
                float a = acc[mi][ni] + bl[tn * 4 + ni];
                float b = acc[mi][ni + 4] + bl[64 + tn * 4 + ni];
                if (RELU) { a = fmaxf(a, 0.0f); b = fmaxf(b, 0.0f); }
                p0[ni] = a; p1[ni] = b;
            }
            *(float4*)&out[n * HID + tn * 4]      = v0;
            *(float4*)&out[n * HID + 64 + tn * 4] = v1;
        }
    }
}

// ---------------- split fp32 -> packed interleaved [hi8|lo8] groups ----------------
// group i (8 consecutive floats) -> 16 ush at outp + i*16: [hi0..hi7, lo0..lo7]
__global__ void split_pack(const float* __restrict__ in, unsigned short* __restrict__ outp,
                           int ngroups) {
    int i = blockIdx.x * blockDim.x + threadIdx.x;
    if (i >= ngroups) return;
    float4 a = ((const float4*)in)[i * 2];
    float4 b = ((const float4*)in)[i * 2 + 1];
    float f[8] = {a.x, a.y, a.z, a.w, b.x, b.y, b.z, b.w};
    ushort4 h0, h1v, l0, l1;
    unsigned short* hp = (unsigned short*)&h0;   // h0,h1v contiguous? no — fill separately
    unsigned short hv[8], lv[8];
    #pragma unroll
    for (int j = 0; j < 8; ++j) {
        unsigned short hb = f2bf(f[j]);
        hv[j] = hb;
        lv[j] = f2bf(f[j] - bf2f(hb));
    }
    h0  = make_ushort4(hv[0], hv[1], hv[2], hv[3]);
    h1v = make_ushort4(hv[4], hv[5], hv[6], hv[7]);
    l0  = make_ushort4(lv[0], lv[1], lv[2], lv[3]);
    l1  = make_ushort4(lv[4], lv[5], lv[6], lv[7]);
    ushort4* dst = (ushort4*)(outp + (size_t)i * 16);
    dst[0] = h0; dst[1] = h1v; dst[2] = l0; dst[3] = l1;
    (void)hp;
}

// ---------------- W1 -> fragment-linear packed [hi8|lo8] ----------------
// element (k,n): c=k/32, q=(k%32)/8, jj=k%8, nt=n/16, r=n%16, lane=q*16+r
// base = ((c*8+nt)*64 + lane)*16 ; hi at base+jj, lo at base+8+jj
__global__ void split_w1(const float* __restrict__ W1, unsigned short* __restrict__ w1p) {
    int tid = blockIdx.x * blockDim.x + threadIdx.x;
    if (tid >= 288 * 128) return;
    int k = tid >> 7, n = tid & 127;
    int c = k >> 5, ko = k & 31, q = ko >> 3, jj = ko & 7;
    int nt = n >> 4, r = n & 15;
    int lane = q * 16 + r;
    int base = ((c * 8 + nt) * 64 + lane) * 16;
    float v = W1[tid];
    unsigned short hb = f2bf(v);
    w1p[base + jj] = hb;
    w1p[base + 8 + jj] = f2bf(v - bf2f(hb));
}

// ---------------- classify: split-bf16 MFMA, 16-edge wave tiles, pipelined gather ----
// Block 256 = 4 waves; 64 edges/block; wave w owns edges [e0+16w, e0+16w+16) x all 128 cols.
// acc = 8 x f32x4 = 32 AGPRs. K = 9 chunks of 32 (4 src, 4 dst, 1 eattr).
__global__ __launch_bounds__(256, 4) void classify_mfma(
    const unsigned short* __restrict__ h1p,
    const int* __restrict__ fsrc, const int* __restrict__ fdst,
    const float* __restrict__ eattr,
    const unsigned short* __restrict__ w1p,
    const float* __restrict__ b1, const float* __restrict__ W2, const float* __restrict__ b2,
    float* __restrict__ out, int Ef)
{
    __shared__ int es[64], ed[64];

    const int t = threadIdx.x;
    const int wave = t >> 6, lane = t & 63;
    const int l15 = lane & 15, quad = lane >> 4;
    const int e0 = blockIdx.x * 64;

    if (t < 64) {
        int e = e0 + t;
        int ec = (e < Ef) ? e : (Ef - 1);
        es[t] = fsrc[ec];
        ed[t] = fdst[ec];
    }
    __syncthreads();

    // hoist eattr load for chunk 8
    int eMine = e0 + wave * 16 + l15;
    if (eMine >= Ef) eMine = Ef - 1;
    const float* pe = eattr + (size_t)eMine * 32 + quad * 8;
    float4 f0 = *(const float4*)pe;
    float4 f1 = *(const float4*)(pe + 4);

    f32x4 acc[8] = {};
    const int midx = wave * 16 + l15;

    // A pipeline: chunk c uses row (c<4 ? src : dst), group (c&3)*4+quad -> offset (c&3)*64+quad*16
    int node0 = es[midx];
    const unsigned short* p0 = h1p + (size_t)node0 * 256 + quad * 16;
    bf16x8 ah = *(const bf16x8*)p0;
    bf16x8 al = *(const bf16x8*)(p0 + 8);

    #pragma unroll
    for (int c = 0; c < 8; ++c) {
        bf16x8 ah2, al2;
        if (c < 7) {
            int cn = c + 1;
            int node = (cn < 4) ? es[midx] : ed[midx];
            const unsigned short* p = h1p + (size_t)node * 256 + (cn & 3) * 64 + quad * 16;
            ah2 = *(const bf16x8*)p;
            al2 = *(const bf16x8*)(p + 8);
        }
        const unsigned short* wp = w1p + ((size_t)(c * 8) * 64 + lane) * 16;
        #pragma unroll
        for (int nt = 0; nt < 8; ++nt) {
            bf16x8 bh = *(const bf16x8*)(wp + nt * 1024);
            bf16x8 bl = *(const bf16x8*)(wp + nt * 1024 + 8);
            acc[nt] = __builtin_amdgcn_mfma_f32_16x16x32_bf16(ah, bh, acc[nt], 0, 0, 0);
            acc[nt] = __builtin_amdgcn_mfma_f32_16x16x32_bf16(ah, bl, acc[nt], 0, 0, 0);
            acc[nt] = __builtin_amdgcn_mfma_f32_16x16x32_bf16(al, bh, acc[nt], 0, 0, 0);
        }
        if (c < 7) { ah = ah2; al = al2; }
    }
    {   // chunk 8: eattr (fp32 -> split in-reg)
        float fv[8] = {f0.x, f0.y, f0.z, f0.w, f1.x, f1.y, f1.z, f1.w};
        bf16x8 ah8, al8;
        #pragma unroll
        for (int j = 0; j < 8; ++j) {
            unsigned short hb = f2bf(fv[j]);
            ah8[j] = (short)hb;
            al8[j] = (short)f2bf(fv[j] - bf2f(hb));
        }
        const unsigned short* wp = w1p + ((size_t)(8 * 8) * 64 + lane) * 16;
        #pragma unroll
        for (int nt = 0; nt < 8; ++nt) {
            bf16x8 bh = *(const bf16x8*)(wp + nt * 1024);
            bf16x8 bl = *(const bf16x8*)(wp + nt * 1024 + 8);
            acc[nt] = __builtin_amdgcn_mfma_f32_16x16x32_bf16(ah8, bh, acc[nt], 0, 0, 0);
            acc[nt] = __builtin_amdgcn_mfma_f32_16x16x32_bf16(ah8, bl, acc[nt], 0, 0, 0);
            acc[nt] = __builtin_amdgcn_mfma_f32_16x16x32_bf16(al8, bh, acc[nt], 0, 0, 0);
        }
    }

    // epilogue: relu(acc + b1) . W2 ; reduce over l15 lanes (cols)
    float b1v[8], w2v[8];
    #pragma unroll
    for (int nt = 0; nt < 8; ++nt) {
        b1v[nt] = b1[nt * 16 + l15];
        w2v[nt] = W2[nt * 16 + l15];
    }
    const float b2s = b2[0];

    #pragma unroll
    for (int reg = 0; reg < 4; ++reg) {
        float s = 0.0f;
        #pragma unroll
        for (int nt = 0; nt < 8; ++nt) {
            float v = acc[nt][reg] + b1v[nt];
            s += fmaxf(v, 0.0f) * w2v[nt];
        }
        s += __shfl_xor(s, 1);
        s += __shfl_xor(s, 2);
        s += __shfl_xor(s, 4);
        s += __shfl_xor(s, 8);
        if (l15 == 0) {
            int e = e0 + wave * 16 + quad * 4 + reg;
            if (e < Ef) out[e] = s + b2s;
        }
    }
}

extern "C" void kernel_launch(void* const* d_in, const int* in_sizes, int n_in,
                              void* d_out, int out_size, void* d_ws, size_t ws_size,
                              hipStream_t stream) {
    const float* x     = (const float*)d_in[0];
    const int*   ei    = (const int*)d_in[1];
    const int*   fei   = (const int*)d_in[2];
    const float* eattr = (const float*)d_in[3];
    const float* Wl0   = (const float*)d_in[4];
    const float* bl0   = (const float*)d_in[5];
    const float* Wr0   = (const float*)d_in[6];
    const float* Wl1   = (const float*)d_in[7];
    const float* bl1   = (const float*)d_in[8];
    const float* Wr1   = (const float*)d_in[9];
    const float* W1    = (const float*)d_in[10];
    const float* b1    = (const float*)d_in[11];
    const float* W2    = (const float*)d_in[12];
    const float* b2    = (const float*)d_in[13];

    const int E  = in_sizes[1] / 2;
    const int Ef = in_sizes[2] / 2;
    const int N  = in_sizes[0] / 64;

    const int* src  = ei;
    const int* dst  = ei + E;
    const int* fsrc = fei;
    const int* fdst = fei + Ef;

    // workspace layout (units: floats)
    float* wsf = (float*)d_ws;
    size_t o = 0;
    int* deg  = (int*)(wsf + o); o += 131072;
    int* off  = (int*)(wsf + o); o += 131072;
    int* pos  = (int*)(wsf + o); o += 131072;
    int* bsum = (int*)(wsf + o); o += 256;
    int* eid  = (int*)(wsf + o); o += 1 << 20;
    unsigned short* w1p = (unsigned short*)(wsf + o); o += 36864;   // 73728 ush
    float* agg = wsf + o; o += (size_t)N * 128;
    float* h   = wsf + o; o += (size_t)N * 128;
    float* h1  = wsf + o; o += (size_t)N * 128;
    unsigned short* h1p = (unsigned short*)agg;   // overlay: agg dead after layer_gemm1
    float* out = (float*)d_out;

    const int nb = (N + 1023) / 1024;

    hipMemsetAsync(deg, 0, (size_t)N * 4, stream);
    degree_kernel<<<(E + 255) / 256, 256, 0, stream>>>(dst, deg, E);
    scan_reduce<<<nb, 256, 0, stream>>>(deg, bsum, N);
    scan_bsum<<<1, 256, 0, stream>>>(bsum, nb);
    scan_final<<<nb, 256, 0, stream>>>(deg, bsum, off, pos, N, E);
    bucket_kernel<<<(E + 255) / 256, 256, 0, stream>>>(src, dst, pos, eid, E);

    split_w1<<<(288 * 128 + 255) / 256, 256, 0, stream>>>(W1, w1p);

    aggregate_kernel<64><<<(N + 3) / 4, 256, 0, stream>>>(x, eid, off, agg, N);
    layer_gemm<64, 64, true><<<(N + 63) / 64, 256, 0, stream>>>(
        agg, x, Wl0, bl0, Wr0, h, N);

    aggregate_kernel<128><<<(N + 3) / 4, 256, 0, stream>>>(h, eid, off, agg, N);
    layer_gemm<128, 128, false><<<(N + 63) / 64, 256, 0, stream>>>(
        agg, h, Wl1, bl1, Wr1, h1, N);

    split_pack<<<((N * 16) + 255) / 256, 256, 0, stream>>>(h1, h1p, N * 16);

    classify_mfma<<<(Ef + 63) / 64, 256, 0, stream>>>(
        h1p, fsrc, fdst, eattr, w1p, b1, W2, b2, out, Ef);
}

// Round 5
// 637.071 us; speedup vs baseline: 1.2166x; 1.2166x over previous
//
#include <hip/hip_runtime.h>

typedef __attribute__((ext_vector_type(8))) short bf16x8;
typedef __attribute__((ext_vector_type(4))) float f32x4;

__device__ inline unsigned short f2bf(float f) {
    unsigned u = __float_as_uint(f);
    unsigned r = (u + 0x7FFF + ((u >> 16) & 1)) >> 16;   // RNE
    return (unsigned short)r;
}
__device__ inline float bf2f(unsigned short h) { return __uint_as_float((unsigned)h << 16); }

// ---------------- CSR build ----------------
__global__ void degree_kernel(const int* __restrict__ dst, int* __restrict__ deg, int E) {
    int e = blockIdx.x * blockDim.x + threadIdx.x;
    if (e < E) atomicAdd(&deg[dst[e]], 1);
}

__global__ void scan_reduce(const int* __restrict__ deg, int* __restrict__ bsum, int N) {
    __shared__ int sd[256];
    int b = blockIdx.x, t = threadIdx.x;
    int base = b * 1024, s = 0;
    for (int i = t; i < 1024; i += 256) {
        int idx = base + i;
        s += (idx < N) ? deg[idx] : 0;
    }
    sd[t] = s; __syncthreads();
    for (int st = 128; st > 0; st >>= 1) {
        if (t < st) sd[t] += sd[t + st];
        __syncthreads();
    }
    if (t == 0) bsum[b] = sd[0];
}

__global__ void scan_bsum(int* __restrict__ bsum, int nb) {
    __shared__ int s[256];
    int t = threadIdx.x;
    int v = (t < nb) ? bsum[t] : 0;
    s[t] = v; __syncthreads();
    for (int st = 1; st < 256; st <<= 1) {
        int add = (t >= st) ? s[t - st] : 0;
        __syncthreads();
        s[t] += add;
        __syncthreads();
    }
    if (t < nb) bsum[t] = s[t] - v;
}

__global__ void scan_final(const int* __restrict__ deg, const int* __restrict__ bsum,
                           int* __restrict__ off, int* __restrict__ pos, int N, int E) {
    __shared__ int ts[256];
    int b = blockIdx.x, t = threadIdx.x, base = b * 1024;
    int v[4], s = 0;
    #pragma unroll
    for (int j = 0; j < 4; ++j) {
        int idx = base + t * 4 + j;
        v[j] = (idx < N) ? deg[idx] : 0;
        s += v[j];
    }
    ts[t] = s; __syncthreads();
    int mine = s;
    for (int st = 1; st < 256; st <<= 1) {
        int add = (t >= st) ? ts[t - st] : 0;
        __syncthreads();
        ts[t] += add;
        __syncthreads();
    }
    int ex = ts[t] - mine + bsum[b];
    #pragma unroll
    for (int j = 0; j < 4; ++j) {
        int idx = base + t * 4 + j;
        if (idx < N) { off[idx] = ex; pos[idx] = ex; }
        ex += v[j];
    }
    if (b == 0 && t == 0) off[N] = E;
}

__global__ void bucket_kernel(const int* __restrict__ src, const int* __restrict__ dst,
                              int* __restrict__ pos, int* __restrict__ eid, int E) {
    int e = blockIdx.x * blockDim.x + threadIdx.x;
    if (e < E) {
        int p = atomicAdd(&pos[dst[e]], 1);
        eid[p] = src[e];
    }
}

// ---------------- aggregate (mean) layer 0: fp32 x input ----------------
__global__ __launch_bounds__(256) void aggregate64(
    const float* __restrict__ feat, const int* __restrict__ eid,
    const int* __restrict__ off, float* __restrict__ agg, int N)
{
    int wave = threadIdx.x >> 6, lane = threadIdx.x & 63;
    int n = blockIdx.x * 4 + wave;
    if (n >= N) return;
    int s0 = __builtin_amdgcn_readfirstlane(off[n]);
    int s1 = __builtin_amdgcn_readfirstlane(off[n + 1]);
    float a = 0.0f;
    int i = s0;
    for (; i + 1 < s1; i += 2) {
        int sa = eid[i], sb = eid[i + 1];
        a += feat[(size_t)sa * 64 + lane] + feat[(size_t)sb * 64 + lane];
    }
    if (i < s1) a += feat[(size_t)eid[i] * 64 + lane];
    float inv = (s1 > s0) ? 1.0f / (float)(s1 - s0) : 0.0f;
    agg[(size_t)n * 64 + lane] = a * inv;
}

// ---------------- aggregate (mean) layer 1: packed [hi8|lo8] h input ----------------
__global__ __launch_bounds__(256) void aggregate128p(
    const unsigned short* __restrict__ hp, const int* __restrict__ eid,
    const int* __restrict__ off, float* __restrict__ agg, int N)
{
    int wave = threadIdx.x >> 6, lane = threadIdx.x & 63;
    int n = blockIdx.x * 4 + wave;
    if (n >= N) return;
    int s0 = __builtin_amdgcn_readfirstlane(off[n]);
    int s1 = __builtin_amdgcn_readfirstlane(off[n + 1]);
    const int g = lane >> 2, p2 = (lane & 3) * 2;   // feats j = lane*2, lane*2+1
    float ax = 0.0f, ay = 0.0f;
    int i = s0;
    for (; i + 1 < s1; i += 2) {
        const unsigned short* pa = hp + (size_t)eid[i] * 256 + g * 16 + p2;
        const unsigned short* pb = hp + (size_t)eid[i + 1] * 256 + g * 16 + p2;
        ushort2 ha = *(const ushort2*)pa, la = *(const ushort2*)(pa + 8);
        ushort2 hb = *(const ushort2*)pb, lb = *(const ushort2*)(pb + 8);
        ax += (bf2f(ha.x) + bf2f(la.x)) + (bf2f(hb.x) + bf2f(lb.x));
        ay += (bf2f(ha.y) + bf2f(la.y)) + (bf2f(hb.y) + bf2f(lb.y));
    }
    if (i < s1) {
        const unsigned short* pa = hp + (size_t)eid[i] * 256 + g * 16 + p2;
        ushort2 ha = *(const ushort2*)pa, la = *(const ushort2*)(pa + 8);
        ax += bf2f(ha.x) + bf2f(la.x);
        ay += bf2f(ha.y) + bf2f(la.y);
    }
    float inv = (s1 > s0) ? 1.0f / (float)(s1 - s0) : 0.0f;
    float2 r; r.x = ax * inv; r.y = ay * inv;
    *(float2*)&agg[(size_t)n * 128 + lane * 2] = r;
}

// ---------------- split fp32 -> packed interleaved [hi8|lo8] groups ----------------
__global__ void split_pack(const float* __restrict__ in, unsigned short* __restrict__ outp,
                           int ngroups) {
    int i = blockIdx.x * blockDim.x + threadIdx.x;
    if (i >= ngroups) return;
    float4 a = ((const float4*)in)[i * 2];
    float4 b = ((const float4*)in)[i * 2 + 1];
    float f[8] = {a.x, a.y, a.z, a.w, b.x, b.y, b.z, b.w};
    unsigned short hv[8], lv[8];
    #pragma unroll
    for (int j = 0; j < 8; ++j) {
        unsigned short hb = f2bf(f[j]);
        hv[j] = hb;
        lv[j] = f2bf(f[j] - bf2f(hb));
    }
    ushort4* dst = (ushort4*)(outp + (size_t)i * 16);
    dst[0] = make_ushort4(hv[0], hv[1], hv[2], hv[3]);
    dst[1] = make_ushort4(hv[4], hv[5], hv[6], hv[7]);
    dst[2] = make_ushort4(lv[0], lv[1], lv[2], lv[3]);
    dst[3] = make_ushort4(lv[4], lv[5], lv[6], lv[7]);
}

// ---------------- weight pack: [Wl;Wr] -> fragment-linear [hi8|lo8] ----------------
// element (k,col): c=k/32, q=(k%32)/8, jj=k%8, nt=col/16, r=col%16, lane=q*16+r
// base = ((c*8+nt)*64 + lane)*16 ; hi at base+jj, lo at base+8+jj
template<int K0, int K1>
__global__ void wpack(const float* __restrict__ Wl, const float* __restrict__ Wr,
                      unsigned short* __restrict__ outp) {
    int tid = blockIdx.x * blockDim.x + threadIdx.x;
    if (tid >= (K0 + K1) * 128) return;
    int k = tid >> 7, col = tid & 127;
    float v = (k < K0) ? Wl[k * 128 + col] : Wr[(k - K0) * 128 + col];
    int c = k >> 5, ko = k & 31, q = ko >> 3, jj = ko & 7;
    int nt = col >> 4, r = col & 15;
    int base = ((c * 8 + nt) * 64 + (q * 16 + r)) * 16;
    unsigned short hb = f2bf(v);
    outp[base + jj] = hb;
    outp[base + 8 + jj] = f2bf(v - bf2f(hb));
}

// W1 (288x128) -> fragment-linear packed (9 chunks)
__global__ void split_w1(const float* __restrict__ W1, unsigned short* __restrict__ w1p) {
    int tid = blockIdx.x * blockDim.x + threadIdx.x;
    if (tid >= 288 * 128) return;
    int k = tid >> 7, n = tid & 127;
    int c = k >> 5, ko = k & 31, q = ko >> 3, jj = ko & 7;
    int nt = n >> 4, r = n & 15;
    int base = ((c * 8 + nt) * 64 + (q * 16 + r)) * 16;
    float v = W1[tid];
    unsigned short hb = f2bf(v);
    w1p[base + jj] = hb;
    w1p[base + 8 + jj] = f2bf(v - bf2f(hb));
}

// ---------------- SAGE layer GEMM: split-bf16 MFMA ----------------
// Block 256 = 4 waves; tile 64 nodes x 128 cols; wave w -> cols [32w, 32w+32).
// A rows node-linear from packed agg (k<K0) / packed dense (k>=K0). Output packed.
template<int K0, int K1, bool RELU>
__global__ __launch_bounds__(256) void mfma_layer(
    const unsigned short* __restrict__ Ap,   // [N][K0/8][16]
    const unsigned short* __restrict__ Xp,   // [N][K1/8][16]
    const unsigned short* __restrict__ Wp,   // fragment-linear packed
    const float* __restrict__ bias,
    unsigned short* __restrict__ outp,       // [N][16][16]
    int N)
{
    constexpr int NC = (K0 + K1) / 32;
    __shared__ float buf[4][64 * 36];        // per-wave 64 nodes x 32 cols, stride 36 (16B-aligned groups)

    const int t = threadIdx.x, wave = t >> 6, lane = t & 63;
    const int l15 = lane & 15, quad = lane >> 4;
    const int n0 = blockIdx.x * 64;

    f32x4 acc[4][2] = {};

    #pragma unroll
    for (int c = 0; c < NC; ++c) {
        bf16x8 ah[4], al[4];
        #pragma unroll
        for (int mt = 0; mt < 4; ++mt) {
            int node = n0 + mt * 16 + l15;
            if (node >= N) node = N - 1;
            const unsigned short* p;
            if (c < K0 / 32)
                p = Ap + ((size_t)node * (K0 / 8) + c * 4 + quad) * 16;
            else
                p = Xp + ((size_t)node * (K1 / 8) + (c - K0 / 32) * 4 + quad) * 16;
            ah[mt] = *(const bf16x8*)p;
            al[mt] = *(const bf16x8*)(p + 8);
        }
        #pragma unroll
        for (int ntl = 0; ntl < 2; ++ntl) {
            const int nt = wave * 2 + ntl;
            const unsigned short* wp = Wp + ((size_t)(c * 8 + nt) * 64 + lane) * 16;
            bf16x8 bh = *(const bf16x8*)wp;
            bf16x8 bl = *(const bf16x8*)(wp + 8);
            #pragma unroll
            for (int mt = 0; mt < 4; ++mt) {
                acc[mt][ntl] = __builtin_amdgcn_mfma_f32_16x16x32_bf16(ah[mt], bh, acc[mt][ntl], 0, 0, 0);
                acc[mt][ntl] = __builtin_amdgcn_mfma_f32_16x16x32_bf16(ah[mt], bl, acc[mt][ntl], 0, 0, 0);
                acc[mt][ntl] = __builtin_amdgcn_mfma_f32_16x16x32_bf16(al[mt], bh, acc[mt][ntl], 0, 0, 0);
            }
        }
    }

    float bv[2];
    bv[0] = bias[wave * 32 + l15];
    bv[1] = bias[wave * 32 + 16 + l15];

    #pragma unroll
    for (int mt = 0; mt < 4; ++mt)
        #pragma unroll
        for (int ntl = 0; ntl < 2; ++ntl)
            #pragma unroll
            for (int reg = 0; reg < 4; ++reg) {
                int node_l = mt * 16 + quad * 4 + reg;
                int col_l  = ntl * 16 + l15;
                float v = acc[mt][ntl][reg] + bv[ntl];
                if (RELU) v = fmaxf(v, 0.0f);
                buf[wave][node_l * 36 + col_l] = v;
            }
    __syncthreads();

    #pragma unroll
    for (int it = 0; it < 4; ++it) {
        int idx = it * 64 + lane;            // 256 groups per wave-tile
        int node_l = idx >> 2, g = idx & 3;  // g: col-group within wave's 32 cols
        float4 v0 = *(const float4*)&buf[wave][node_l * 36 + g * 8];
        float4 v1 = *(const float4*)&buf[wave][node_l * 36 + g * 8 + 4];
        float f[8] = {v0.x, v0.y, v0.z, v0.w, v1.x, v1.y, v1.z, v1.w};
        unsigned short hv[8], lv[8];
        #pragma unroll
        for (int j = 0; j < 8; ++j) {
            unsigned short hb = f2bf(f[j]);
            hv[j] = hb;
            lv[j] = f2bf(f[j] - bf2f(hb));
        }
        int node_g = n0 + node_l;
        if (node_g < N) {
            ushort4* dst = (ushort4*)(outp + ((size_t)node_g * 16 + wave * 4 + g) * 16);
            dst[0] = make_ushort4(hv[0], hv[1], hv[2], hv[3]);
            dst[1] = make_ushort4(hv[4], hv[5], hv[6], hv[7]);
            dst[2] = make_ushort4(lv[0], lv[1], lv[2], lv[3]);
            dst[3] = make_ushort4(lv[4], lv[5], lv[6], lv[7]);
        }
    }
}

// ---------------- classify: split-bf16 MFMA, 32-edge wave tiles (R3 structure, packed) ----
__global__ __launch_bounds__(256) void classify_mfma(
    const unsigned short* __restrict__ h1p,
    const int* __restrict__ fsrc, const int* __restrict__ fdst,
    const float* __restrict__ eattr,
    const unsigned short* __restrict__ w1p,
    const float* __restrict__ b1, const float* __restrict__ W2, const float* __restrict__ b2,
    float* __restrict__ out, int Ef)
{
    __shared__ int es[128], ed[128];

    const int t = threadIdx.x;
    const int wave = t >> 6, lane = t & 63;
    const int l15 = lane & 15, quad = lane >> 4;
    const int e0 = blockIdx.x * 128;

    if (t < 128) {
        int e = e0 + t;
        int ec = (e < Ef) ? e : (Ef - 1);
        es[t] = fsrc[ec];
        ed[t] = fdst[ec];
    }
    __syncthreads();

    f32x4 acc[2][8] = {};
    const int m0 = wave * 32 + l15;

    #pragma unroll
    for (int kc = 0; kc < 8; ++kc) {
        bf16x8 ah[2], al[2];
        #pragma unroll
        for (int mt = 0; mt < 2; ++mt) {
            int node = (kc < 4) ? es[m0 + mt * 16] : ed[m0 + mt * 16];
            const unsigned short* p = h1p + (size_t)node * 256 + (kc & 3) * 64 + quad * 16;
            ah[mt] = *(const bf16x8*)p;
            al[mt] = *(const bf16x8*)(p + 8);
        }
        const unsigned short* wp = w1p + ((size_t)(kc * 8) * 64 + lane) * 16;
        #pragma unroll
        for (int nt = 0; nt < 8; ++nt) {
            bf16x8 bh = *(const bf16x8*)(wp + nt * 1024);
            bf16x8 bl = *(const bf16x8*)(wp + nt * 1024 + 8);
            #pragma unroll
            for (int mt = 0; mt < 2; ++mt) {
                acc[mt][nt] = __builtin_amdgcn_mfma_f32_16x16x32_bf16(ah[mt], bh, acc[mt][nt], 0, 0, 0);
                acc[mt][nt] = __builtin_amdgcn_mfma_f32_16x16x32_bf16(ah[mt], bl, acc[mt][nt], 0, 0, 0);
                acc[mt][nt] = __builtin_amdgcn_mfma_f32_16x16x32_bf16(al[mt], bh, acc[mt][nt], 0, 0, 0);
            }
        }
    }
    {   // chunk 8: eattr (fp32 -> split in-reg)
        #pragma unroll
        for (int mt = 0; mt < 2; ++mt) {
            int e = e0 + wave * 32 + mt * 16 + l15;
            if (e >= Ef) e = Ef - 1;
            const float* pe = eattr + (size_t)e * 32 + quad * 8;
            float4 f0 = *(const float4*)pe;
            float4 f1 = *(const float4*)(pe + 4);
            float fv[8] = {f0.x, f0.y, f0.z, f0.w, f1.x, f1.y, f1.z, f1.w};
            bf16x8 ah8, al8;
            #pragma unroll
            for (int j = 0; j < 8; ++j) {
                unsigned short hb = f2bf(fv[j]);
                ah8[j] = (short)hb;
                al8[j] = (short)f2bf(fv[j] - bf2f(hb));
            }
            const unsigned short* wp = w1p + ((size_t)(8 * 8) * 64 + lane) * 16;
            #pragma unroll
            for (int nt = 0; nt < 8; ++nt) {
                bf16x8 bh = *(const bf16x8*)(wp + nt * 1024);
                bf16x8 bl = *(const bf16x8*)(wp + nt * 1024 + 8);
                acc[mt][nt] = __builtin_amdgcn_mfma_f32_16x16x32_bf16(ah8, bh, acc[mt][nt], 0, 0, 0);
                acc[mt][nt] = __builtin_amdgcn_mfma_f32_16x16x32_bf16(ah8, bl, acc[mt][nt], 0, 0, 0);
                acc[mt][nt] = __builtin_amdgcn_mfma_f32_16x16x32_bf16(al8, bh, acc[mt][nt], 0, 0, 0);
            }
        }
    }

    float b1v[8], w2v[8];
    #pragma unroll
    for (int nt = 0; nt < 8; ++nt) {
        b1v[nt] = b1[nt * 16 + l15];
        w2v[nt] = W2[nt * 16 + l15];
    }
    const float b2s = b2[0];

    #pragma unroll
    for (int mt = 0; mt < 2; ++mt) {
        #pragma unroll
        for (int reg = 0; reg < 4; ++reg) {
            float s = 0.0f;
            #pragma unroll
            for (int nt = 0; nt < 8; ++nt) {
                float v = acc[mt][nt][reg] + b1v[nt];
                s += fmaxf(v, 0.0f) * w2v[nt];
            }
            s += __shfl_xor(s, 1);
            s += __shfl_xor(s, 2);
            s += __shfl_xor(s, 4);
            s += __shfl_xor(s, 8);
            if (l15 == 0) {
                int e = e0 + wave * 32 + mt * 16 + quad * 4 + reg;
                if (e < Ef) out[e] = s + b2s;
            }
        }
    }
}

extern "C" void kernel_launch(void* const* d_in, const int* in_sizes, int n_in,
                              void* d_out, int out_size, void* d_ws, size_t ws_size,
                              hipStream_t stream) {
    const float* x     = (const float*)d_in[0];
    const int*   ei    = (const int*)d_in[1];
    const int*   fei   = (const int*)d_in[2];
    const float* eattr = (const float*)d_in[3];
    const float* Wl0   = (const float*)d_in[4];
    const float* bl0   = (const float*)d_in[5];
    const float* Wr0   = (const float*)d_in[6];
    const float* Wl1   = (const float*)d_in[7];
    const float* bl1   = (const float*)d_in[8];
    const float* Wr1   = (const float*)d_in[9];
    const float* W1    = (const float*)d_in[10];
    const float* b1    = (const float*)d_in[11];
    const float* W2    = (const float*)d_in[12];
    const float* b2    = (const float*)d_in[13];

    const int E  = in_sizes[1] / 2;
    const int Ef = in_sizes[2] / 2;
    const int N  = in_sizes[0] / 64;

    const int* src  = ei;
    const int* dst  = ei + E;
    const int* fsrc = fei;
    const int* fdst = fei + Ef;

    // workspace layout (units: floats). Packed arrays have same byte size as fp32 source.
    float* wsf = (float*)d_ws;
    size_t o = 0;
    int* deg  = (int*)(wsf + o); o += 131072;
    int* off  = (int*)(wsf + o); o += 131072;
    int* pos  = (int*)(wsf + o); o += 131072;
    int* bsum = (int*)(wsf + o); o += 256;
    int* eid  = (int*)(wsf + o); o += 1 << 20;
    unsigned short* w0p = (unsigned short*)(wsf + o); o += 16384;   // 128*128 packed
    unsigned short* wLp = (unsigned short*)(wsf + o); o += 32768;   // 256*128 packed
    unsigned short* w1p = (unsigned short*)(wsf + o); o += 36864;   // 288*128 packed
    unsigned short* xp  = (unsigned short*)(wsf + o); o += (size_t)N * 64;   // N x 64 packed
    unsigned short* aggp= (unsigned short*)(wsf + o); o += (size_t)N * 128;  // up to N x 128 packed
    unsigned short* h_p = (unsigned short*)(wsf + o); o += (size_t)N * 128;  // N x 128 packed
    float* agg = wsf + o; o += (size_t)N * 128;                              // fp32 scratch
    unsigned short* h1p = (unsigned short*)agg;        // overlay: agg dead after final split_pack
    float* out = (float*)d_out;

    const int nb = (N + 1023) / 1024;

    hipMemsetAsync(deg, 0, (size_t)N * 4, stream);
    degree_kernel<<<(E + 255) / 256, 256, 0, stream>>>(dst, deg, E);
    scan_reduce<<<nb, 256, 0, stream>>>(deg, bsum, N);
    scan_bsum<<<1, 256, 0, stream>>>(bsum, nb);
    scan_final<<<nb, 256, 0, stream>>>(deg, bsum, off, pos, N, E);
    bucket_kernel<<<(E + 255) / 256, 256, 0, stream>>>(src, dst, pos, eid, E);

    wpack<64, 64><<<(128 * 128 + 255) / 256, 256, 0, stream>>>(Wl0, Wr0, w0p);
    wpack<128, 128><<<(256 * 128 + 255) / 256, 256, 0, stream>>>(Wl1, Wr1, wLp);
    split_w1<<<(288 * 128 + 255) / 256, 256, 0, stream>>>(W1, w1p);

    split_pack<<<((N * 8) + 255) / 256, 256, 0, stream>>>(x, xp, N * 8);

    aggregate64<<<(N + 3) / 4, 256, 0, stream>>>(x, eid, off, agg, N);
    split_pack<<<((N * 8) + 255) / 256, 256, 0, stream>>>(agg, aggp, N * 8);
    mfma_layer<64, 64, true><<<(N + 63) / 64, 256, 0, stream>>>(
        aggp, xp, w0p, bl0, h_p, N);

    aggregate128p<<<(N + 3) / 4, 256, 0, stream>>>(h_p, eid, off, agg, N);
    split_pack<<<((N * 16) + 255) / 256, 256, 0, stream>>>(agg, aggp, N * 16);
    mfma_layer<128, 128, false><<<(N + 63) / 64, 256, 0, stream>>>(
        aggp, h_p, wLp, bl1, h1p, N);

    classify_mfma<<<(Ef + 127) / 128, 256, 0, stream>>>(
        h1p, fsrc, fdst, eattr, w1p, b1, W2, b2, out, Ef);
}

// Round 6
// 601.322 us; speedup vs baseline: 1.2889x; 1.0595x over previous
//
#include <hip/hip_runtime.h>

typedef __attribute__((ext_vector_type(8))) short bf16x8;
typedef __attribute__((ext_vector_type(4))) float f32x4;

__device__ inline unsigned short f2bf(float f) {
    unsigned u = __float_as_uint(f);
    unsigned r = (u + 0x7FFF + ((u >> 16) & 1)) >> 16;   // RNE
    return (unsigned short)r;
}
__device__ inline float bf2f(unsigned short h) { return __uint_as_float((unsigned)h << 16); }

// ---------------- CSR build ----------------
__global__ void degree_kernel(const int* __restrict__ dst, int* __restrict__ deg, int E) {
    int e = blockIdx.x * blockDim.x + threadIdx.x;
    if (e < E) atomicAdd(&deg[dst[e]], 1);
}

__global__ void scan_reduce(const int* __restrict__ deg, int* __restrict__ bsum, int N) {
    __shared__ int sd[256];
    int b = blockIdx.x, t = threadIdx.x;
    int base = b * 1024, s = 0;
    for (int i = t; i < 1024; i += 256) {
        int idx = base + i;
        s += (idx < N) ? deg[idx] : 0;
    }
    sd[t] = s; __syncthreads();
    for (int st = 128; st > 0; st >>= 1) {
        if (t < st) sd[t] += sd[t + st];
        __syncthreads();
    }
    if (t == 0) bsum[b] = sd[0];
}

__global__ void scan_bsum(int* __restrict__ bsum, int nb) {
    __shared__ int s[256];
    int t = threadIdx.x;
    int v = (t < nb) ? bsum[t] : 0;
    s[t] = v; __syncthreads();
    for (int st = 1; st < 256; st <<= 1) {
        int add = (t >= st) ? s[t - st] : 0;
        __syncthreads();
        s[t] += add;
        __syncthreads();
    }
    if (t < nb) bsum[t] = s[t] - v;
}

__global__ void scan_final(const int* __restrict__ deg, const int* __restrict__ bsum,
                           int* __restrict__ off, int* __restrict__ pos, int N, int E) {
    __shared__ int ts[256];
    int b = blockIdx.x, t = threadIdx.x, base = b * 1024;
    int v[4], s = 0;
    #pragma unroll
    for (int j = 0; j < 4; ++j) {
        int idx = base + t * 4 + j;
        v[j] = (idx < N) ? deg[idx] : 0;
        s += v[j];
    }
    ts[t] = s; __syncthreads();
    int mine = s;
    for (int st = 1; st < 256; st <<= 1) {
        int add = (t >= st) ? ts[t - st] : 0;
        __syncthreads();
        ts[t] += add;
        __syncthreads();
    }
    int ex = ts[t] - mine + bsum[b];
    #pragma unroll
    for (int j = 0; j < 4; ++j) {
        int idx = base + t * 4 + j;
        if (idx < N) { off[idx] = ex; pos[idx] = ex; }
        ex += v[j];
    }
    if (b == 0 && t == 0) off[N] = E;
}

__global__ void bucket_kernel(const int* __restrict__ src, const int* __restrict__ dst,
                              int* __restrict__ pos, int* __restrict__ eid, int E) {
    int e = blockIdx.x * blockDim.x + threadIdx.x;
    if (e < E) {
        int p = atomicAdd(&pos[dst[e]], 1);
        eid[p] = src[e];
    }
}

// ---------------- aggregate (mean) layer 0: fp32 x input ----------------
__global__ __launch_bounds__(256) void aggregate64(
    const float* __restrict__ feat, const int* __restrict__ eid,
    const int* __restrict__ off, float* __restrict__ agg, int N)
{
    int wave = threadIdx.x >> 6, lane = threadIdx.x & 63;
    int n = blockIdx.x * 4 + wave;
    if (n >= N) return;
    int s0 = __builtin_amdgcn_readfirstlane(off[n]);
    int s1 = __builtin_amdgcn_readfirstlane(off[n + 1]);
    float a = 0.0f;
    int i = s0;
    for (; i + 3 < s1; i += 4) {
        int sa = eid[i], sb = eid[i + 1], sc = eid[i + 2], sd = eid[i + 3];
        a += feat[(size_t)sa * 64 + lane] + feat[(size_t)sb * 64 + lane]
           + feat[(size_t)sc * 64 + lane] + feat[(size_t)sd * 64 + lane];
    }
    for (; i < s1; ++i) a += feat[(size_t)eid[i] * 64 + lane];
    float inv = (s1 > s0) ? 1.0f / (float)(s1 - s0) : 0.0f;
    agg[(size_t)n * 64 + lane] = a * inv;
}

// ---------------- aggregate (mean) layer 1: bf16-hi h input ----------------
__global__ __launch_bounds__(256) void aggregate128h(
    const unsigned short* __restrict__ h_hi, const int* __restrict__ eid,
    const int* __restrict__ off, float* __restrict__ agg, int N)
{
    int wave = threadIdx.x >> 6, lane = threadIdx.x & 63;
    int n = blockIdx.x * 4 + wave;
    if (n >= N) return;
    int s0 = __builtin_amdgcn_readfirstlane(off[n]);
    int s1 = __builtin_amdgcn_readfirstlane(off[n + 1]);
    float ax = 0.0f, ay = 0.0f;
    int i = s0;
    for (; i + 3 < s1; i += 4) {
        ushort2 va = *(const ushort2*)(h_hi + (size_t)eid[i]     * 128 + lane * 2);
        ushort2 vb = *(const ushort2*)(h_hi + (size_t)eid[i + 1] * 128 + lane * 2);
        ushort2 vc = *(const ushort2*)(h_hi + (size_t)eid[i + 2] * 128 + lane * 2);
        ushort2 vd = *(const ushort2*)(h_hi + (size_t)eid[i + 3] * 128 + lane * 2);
        ax += (bf2f(va.x) + bf2f(vb.x)) + (bf2f(vc.x) + bf2f(vd.x));
        ay += (bf2f(va.y) + bf2f(vb.y)) + (bf2f(vc.y) + bf2f(vd.y));
    }
    for (; i < s1; ++i) {
        ushort2 va = *(const ushort2*)(h_hi + (size_t)eid[i] * 128 + lane * 2);
        ax += bf2f(va.x); ay += bf2f(va.y);
    }
    float inv = (s1 > s0) ? 1.0f / (float)(s1 - s0) : 0.0f;
    float2 r; r.x = ax * inv; r.y = ay * inv;
    *(float2*)&agg[(size_t)n * 128 + lane * 2] = r;
}

// ---------------- split fp32 -> packed interleaved [hi8|lo8] groups ----------------
__global__ void split_pack(const float* __restrict__ in, unsigned short* __restrict__ outp,
                           int ngroups) {
    int i = blockIdx.x * blockDim.x + threadIdx.x;
    if (i >= ngroups) return;
    float4 a = ((const float4*)in)[i * 2];
    float4 b = ((const float4*)in)[i * 2 + 1];
    float f[8] = {a.x, a.y, a.z, a.w, b.x, b.y, b.z, b.w};
    unsigned short hv[8], lv[8];
    #pragma unroll
    for (int j = 0; j < 8; ++j) {
        unsigned short hb = f2bf(f[j]);
        hv[j] = hb;
        lv[j] = f2bf(f[j] - bf2f(hb));
    }
    ushort4* dst = (ushort4*)(outp + (size_t)i * 16);
    dst[0] = make_ushort4(hv[0], hv[1], hv[2], hv[3]);
    dst[1] = make_ushort4(hv[4], hv[5], hv[6], hv[7]);
    dst[2] = make_ushort4(lv[0], lv[1], lv[2], lv[3]);
    dst[3] = make_ushort4(lv[4], lv[5], lv[6], lv[7]);
}

// ---------------- weight pack: [Wl;Wr] -> fragment-linear [hi8|lo8] ----------------
template<int K0, int K1>
__global__ void wpack(const float* __restrict__ Wl, const float* __restrict__ Wr,
                      unsigned short* __restrict__ outp) {
    int tid = blockIdx.x * blockDim.x + threadIdx.x;
    if (tid >= (K0 + K1) * 128) return;
    int k = tid >> 7, col = tid & 127;
    float v = (k < K0) ? Wl[k * 128 + col] : Wr[(k - K0) * 128 + col];
    int c = k >> 5, ko = k & 31, q = ko >> 3, jj = ko & 7;
    int nt = col >> 4, r = col & 15;
    int base = ((c * 8 + nt) * 64 + (q * 16 + r)) * 16;
    unsigned short hb = f2bf(v);
    outp[base + jj] = hb;
    outp[base + 8 + jj] = f2bf(v - bf2f(hb));
}

__global__ void split_w1(const float* __restrict__ W1, unsigned short* __restrict__ w1p) {
    int tid = blockIdx.x * blockDim.x + threadIdx.x;
    if (tid >= 288 * 128) return;
    int k = tid >> 7, n = tid & 127;
    int c = k >> 5, ko = k & 31, q = ko >> 3, jj = ko & 7;
    int nt = n >> 4, r = n & 15;
    int base = ((c * 8 + nt) * 64 + (q * 16 + r)) * 16;
    float v = W1[tid];
    unsigned short hb = f2bf(v);
    w1p[base + jj] = hb;
    w1p[base + 8 + jj] = f2bf(v - bf2f(hb));
}

// ---------------- SAGE layer GEMM: split-bf16 MFMA ----------------
// Block 256 = 4 waves; tile 64 nodes x 128 cols; wave w -> cols [32w, 32w+32).
// Outputs: packed [hi8|lo8] (WPACK) and/or bf16-hi linear rows (WHI).
template<int K0, int K1, bool RELU, bool WPACK, bool WHI>
__global__ __launch_bounds__(256) void mfma_layer(
    const unsigned short* __restrict__ Ap,   // [N][K0/8][16]
    const unsigned short* __restrict__ Xp,   // [N][K1/8][16]
    const unsigned short* __restrict__ Wp,   // fragment-linear packed
    const float* __restrict__ bias,
    unsigned short* __restrict__ outp,       // [N][16][16] packed (if WPACK)
    unsigned short* __restrict__ outh,       // [N][128] bf16-hi (if WHI)
    int N)
{
    constexpr int NC = (K0 + K1) / 32;
    __shared__ float buf[4][64 * 36];

    const int t = threadIdx.x, wave = t >> 6, lane = t & 63;
    const int l15 = lane & 15, quad = lane >> 4;
    const int n0 = blockIdx.x * 64;

    f32x4 acc[4][2] = {};

    #pragma unroll
    for (int c = 0; c < NC; ++c) {
        bf16x8 ah[4], al[4];
        #pragma unroll
        for (int mt = 0; mt < 4; ++mt) {
            int node = n0 + mt * 16 + l15;
            if (node >= N) node = N - 1;
            const unsigned short* p;
            if (c < K0 / 32)
                p = Ap + ((size_t)node * (K0 / 8) + c * 4 + quad) * 16;
            else
                p = Xp + ((size_t)node * (K1 / 8) + (c - K0 / 32) * 4 + quad) * 16;
            ah[mt] = *(const bf16x8*)p;
            al[mt] = *(const bf16x8*)(p + 8);
        }
        #pragma unroll
        for (int ntl = 0; ntl < 2; ++ntl) {
            const int nt = wave * 2 + ntl;
            const unsigned short* wp = Wp + ((size_t)(c * 8 + nt) * 64 + lane) * 16;
            bf16x8 bh = *(const bf16x8*)wp;
            bf16x8 bl = *(const bf16x8*)(wp + 8);
            #pragma unroll
            for (int mt = 0; mt < 4; ++mt) {
                acc[mt][ntl] = __builtin_amdgcn_mfma_f32_16x16x32_bf16(ah[mt], bh, acc[mt][ntl], 0, 0, 0);
                acc[mt][ntl] = __builtin_amdgcn_mfma_f32_16x16x32_bf16(ah[mt], bl, acc[mt][ntl], 0, 0, 0);
                acc[mt][ntl] = __builtin_amdgcn_mfma_f32_16x16x32_bf16(al[mt], bh, acc[mt][ntl], 0, 0, 0);
            }
        }
    }

    float bv[2];
    bv[0] = bias[wave * 32 + l15];
    bv[1] = bias[wave * 32 + 16 + l15];

    #pragma unroll
    for (int mt = 0; mt < 4; ++mt)
        #pragma unroll
        for (int ntl = 0; ntl < 2; ++ntl)
            #pragma unroll
            for (int reg = 0; reg < 4; ++reg) {
                int node_l = mt * 16 + quad * 4 + reg;
                int col_l  = ntl * 16 + l15;
                float v = acc[mt][ntl][reg] + bv[ntl];
                if (RELU) v = fmaxf(v, 0.0f);
                buf[wave][node_l * 36 + col_l] = v;
            }
    __syncthreads();

    #pragma unroll
    for (int it = 0; it < 4; ++it) {
        int idx = it * 64 + lane;
        int node_l = idx >> 2, g = idx & 3;
        float4 v0 = *(const float4*)&buf[wave][node_l * 36 + g * 8];
        float4 v1 = *(const float4*)&buf[wave][node_l * 36 + g * 8 + 4];
        float f[8] = {v0.x, v0.y, v0.z, v0.w, v1.x, v1.y, v1.z, v1.w};
        bf16x8 hvv;
        unsigned short hv[8], lv[8];
        #pragma unroll
        for (int j = 0; j < 8; ++j) {
            unsigned short hb = f2bf(f[j]);
            hv[j] = hb;
            hvv[j] = (short)hb;
            if (WPACK) lv[j] = f2bf(f[j] - bf2f(hb));
        }
        int node_g = n0 + node_l;
        if (node_g < N) {
            if (WPACK) {
                ushort4* dst = (ushort4*)(outp + ((size_t)node_g * 16 + wave * 4 + g) * 16);
                dst[0] = make_ushort4(hv[0], hv[1], hv[2], hv[3]);
                dst[1] = make_ushort4(hv[4], hv[5], hv[6], hv[7]);
                dst[2] = make_ushort4(lv[0], lv[1], lv[2], lv[3]);
                dst[3] = make_ushort4(lv[4], lv[5], lv[6], lv[7]);
            }
            if (WHI)
                *(bf16x8*)(outh + (size_t)node_g * 128 + wave * 32 + g * 8) = hvv;
        }
    }
}

// ---------------- classify: A = bf16-hi h1 gather, B = split-bf16 W1, 2-pass ----------
__global__ __launch_bounds__(256, 4) void classify_mfma(
    const unsigned short* __restrict__ h1h,
    const int* __restrict__ fsrc, const int* __restrict__ fdst,
    const float* __restrict__ eattr,
    const unsigned short* __restrict__ w1p,
    const float* __restrict__ b1, const float* __restrict__ W2, const float* __restrict__ b2,
    float* __restrict__ out, int Ef)
{
    __shared__ int es[128], ed[128];

    const int t = threadIdx.x;
    const int wave = t >> 6, lane = t & 63;
    const int l15 = lane & 15, quad = lane >> 4;
    const int e0 = blockIdx.x * 128;

    if (t < 128) {
        int e = e0 + t;
        int ec = (e < Ef) ? e : (Ef - 1);
        es[t] = fsrc[ec];
        ed[t] = fdst[ec];
    }
    __syncthreads();

    f32x4 acc[2][8] = {};
    const int m0 = wave * 32 + l15;

    #pragma unroll
    for (int kc = 0; kc < 8; ++kc) {
        bf16x8 ah[2];
        #pragma unroll
        for (int mt = 0; mt < 2; ++mt) {
            int node = (kc < 4) ? es[m0 + mt * 16] : ed[m0 + mt * 16];
            ah[mt] = *(const bf16x8*)(h1h + (size_t)node * 128 + (kc & 3) * 32 + quad * 8);
        }
        const unsigned short* wp = w1p + ((size_t)(kc * 8) * 64 + lane) * 16;
        #pragma unroll
        for (int nt = 0; nt < 8; ++nt) {
            bf16x8 bh = *(const bf16x8*)(wp + nt * 1024);
            bf16x8 bl = *(const bf16x8*)(wp + nt * 1024 + 8);
            #pragma unroll
            for (int mt = 0; mt < 2; ++mt) {
                acc[mt][nt] = __builtin_amdgcn_mfma_f32_16x16x32_bf16(ah[mt], bh, acc[mt][nt], 0, 0, 0);
                acc[mt][nt] = __builtin_amdgcn_mfma_f32_16x16x32_bf16(ah[mt], bl, acc[mt][nt], 0, 0, 0);
            }
        }
    }
    {   // chunk 8: eattr (fp32 -> bf16 hi in-reg)
        #pragma unroll
        for (int mt = 0; mt < 2; ++mt) {
            int e = e0 + wave * 32 + mt * 16 + l15;
            if (e >= Ef) e = Ef - 1;
            const float* pe = eattr + (size_t)e * 32 + quad * 8;
            float4 f0 = *(const float4*)pe;
            float4 f1 = *(const float4*)(pe + 4);
            float fv[8] = {f0.x, f0.y, f0.z, f0.w, f1.x, f1.y, f1.z, f1.w};
            bf16x8 ah8;
            #pragma unroll
            for (int j = 0; j < 8; ++j) ah8[j] = (short)f2bf(fv[j]);
            const unsigned short* wp = w1p + ((size_t)(8 * 8) * 64 + lane) * 16;
            #pragma unroll
            for (int nt = 0; nt < 8; ++nt) {
                bf16x8 bh = *(const bf16x8*)(wp + nt * 1024);
                bf16x8 bl = *(const bf16x8*)(wp + nt * 1024 + 8);
                acc[mt][nt] = __builtin_amdgcn_mfma_f32_16x16x32_bf16(ah8, bh, acc[mt][nt], 0, 0, 0);
                acc[mt][nt] = __builtin_amdgcn_mfma_f32_16x16x32_bf16(ah8, bl, acc[mt][nt], 0, 0, 0);
            }
        }
    }

    float b1v[8], w2v[8];
    #pragma unroll
    for (int nt = 0; nt < 8; ++nt) {
        b1v[nt] = b1[nt * 16 + l15];
        w2v[nt] = W2[nt * 16 + l15];
    }
    const float b2s = b2[0];

    #pragma unroll
    for (int mt = 0; mt < 2; ++mt) {
        #pragma unroll
        for (int reg = 0; reg < 4; ++reg) {
            float s = 0.0f;
            #pragma unroll
            for (int nt = 0; nt < 8; ++nt) {
                float v = acc[mt][nt][reg] + b1v[nt];
                s += fmaxf(v, 0.0f) * w2v[nt];
            }
            s += __shfl_xor(s, 1);
            s += __shfl_xor(s, 2);
            s += __shfl_xor(s, 4);
            s += __shfl_xor(s, 8);
            if (l15 == 0) {
                int e = e0 + wave * 32 + mt * 16 + quad * 4 + reg;
                if (e < Ef) out[e] = s + b2s;
            }
        }
    }
}

extern "C" void kernel_launch(void* const* d_in, const int* in_sizes, int n_in,
                              void* d_out, int out_size, void* d_ws, size_t ws_size,
                              hipStream_t stream) {
    const float* x     = (const float*)d_in[0];
    const int*   ei    = (const int*)d_in[1];
    const int*   fei   = (const int*)d_in[2];
    const float* eattr = (const float*)d_in[3];
    const float* Wl0   = (const float*)d_in[4];
    const float* bl0   = (const float*)d_in[5];
    const float* Wr0   = (const float*)d_in[6];
    const float* Wl1   = (const float*)d_in[7];
    const float* bl1   = (const float*)d_in[8];
    const float* Wr1   = (const float*)d_in[9];
    const float* W1    = (const float*)d_in[10];
    const float* b1    = (const float*)d_in[11];
    const float* W2    = (const float*)d_in[12];
    const float* b2    = (const float*)d_in[13];

    const int E  = in_sizes[1] / 2;
    const int Ef = in_sizes[2] / 2;
    const int N  = in_sizes[0] / 64;

    const int* src  = ei;
    const int* dst  = ei + E;
    const int* fsrc = fei;
    const int* fdst = fei + Ef;

    // workspace layout (units: floats)
    float* wsf = (float*)d_ws;
    size_t o = 0;
    int* deg  = (int*)(wsf + o); o += 131072;
    int* off  = (int*)(wsf + o); o += 131072;
    int* pos  = (int*)(wsf + o); o += 131072;
    int* bsum = (int*)(wsf + o); o += 256;
    int* eid  = (int*)(wsf + o); o += 1 << 20;
    unsigned short* w0p = (unsigned short*)(wsf + o); o += 16384;
    unsigned short* wLp = (unsigned short*)(wsf + o); o += 32768;
    unsigned short* w1p = (unsigned short*)(wsf + o); o += 36864;
    unsigned short* xp  = (unsigned short*)(wsf + o); o += (size_t)N * 64;   // packed x (layer0 dense)
    unsigned short* h_p = (unsigned short*)(wsf + o); o += (size_t)N * 128;  // packed h (layer1 dense)
    float* agg          = wsf + o;                    o += (size_t)N * 128;  // fp32 agg scratch
    unsigned short* aggp= (unsigned short*)(wsf + o); o += (size_t)N * 128;  // packed agg

    // overlays (block-local or phase-disjoint lifetimes):
    unsigned short* h_hi  = xp;                 // written by mfma_layer0 epilogue (xp rows are block-local)
    unsigned short* h1_hi = (unsigned short*)agg; // agg dead after second split_pack
    float* out = (float*)d_out;

    const int nb = (N + 1023) / 1024;

    hipMemsetAsync(deg, 0, (size_t)N * 4, stream);
    degree_kernel<<<(E + 255) / 256, 256, 0, stream>>>(dst, deg, E);
    scan_reduce<<<nb, 256, 0, stream>>>(deg, bsum, N);
    scan_bsum<<<1, 256, 0, stream>>>(bsum, nb);
    scan_final<<<nb, 256, 0, stream>>>(deg, bsum, off, pos, N, E);
    bucket_kernel<<<(E + 255) / 256, 256, 0, stream>>>(src, dst, pos, eid, E);

    wpack<64, 64><<<(128 * 128 + 255) / 256, 256, 0, stream>>>(Wl0, Wr0, w0p);
    wpack<128, 128><<<(256 * 128 + 255) / 256, 256, 0, stream>>>(Wl1, Wr1, wLp);
    split_w1<<<(288 * 128 + 255) / 256, 256, 0, stream>>>(W1, w1p);

    split_pack<<<((N * 8) + 255) / 256, 256, 0, stream>>>(x, xp, N * 8);

    aggregate64<<<(N + 3) / 4, 256, 0, stream>>>(x, eid, off, agg, N);
    split_pack<<<((N * 8) + 255) / 256, 256, 0, stream>>>(agg, aggp, N * 8);
    mfma_layer<64, 64, true, true, true><<<(N + 63) / 64, 256, 0, stream>>>(
        aggp, xp, w0p, bl0, h_p, h_hi, N);

    aggregate128h<<<(N + 3) / 4, 256, 0, stream>>>(h_hi, eid, off, agg, N);
    split_pack<<<((N * 16) + 255) / 256, 256, 0, stream>>>(agg, aggp, N * 16);
    mfma_layer<128, 128, false, false, true><<<(N + 63) / 64, 256, 0, stream>>>(
        aggp, h_p, wLp, bl1, nullptr, h1_hi, N);

    classify_mfma<<<(Ef + 127) / 128, 256, 0, stream>>>(
        h1_hi, fsrc, fdst, eattr, w1p, b1, W2, b2, out, Ef);
}

// Round 7
// 549.200 us; speedup vs baseline: 1.4113x; 1.0949x over previous
//
#include <hip/hip_runtime.h>

typedef __attribute__((ext_vector_type(8))) short bf16x8;
typedef __attribute__((ext_vector_type(4))) float f32x4;

__device__ inline unsigned short f2bf(float f) {
    unsigned u = __float_as_uint(f);
    unsigned r = (u + 0x7FFF + ((u >> 16) & 1)) >> 16;   // RNE
    return (unsigned short)r;
}
__device__ inline float bf2f(unsigned short h) { return __uint_as_float((unsigned)h << 16); }

// ---------------- CSR build ----------------
__global__ void degree_kernel(const int* __restrict__ dst, int* __restrict__ deg, int E) {
    int e = blockIdx.x * blockDim.x + threadIdx.x;
    if (e < E) atomicAdd(&deg[dst[e]], 1);
}

__global__ void scan_reduce(const int* __restrict__ deg, int* __restrict__ bsum, int N) {
    __shared__ int sd[256];
    int b = blockIdx.x, t = threadIdx.x;
    int base = b * 1024, s = 0;
    for (int i = t; i < 1024; i += 256) {
        int idx = base + i;
        s += (idx < N) ? deg[idx] : 0;
    }
    sd[t] = s; __syncthreads();
    for (int st = 128; st > 0; st >>= 1) {
        if (t < st) sd[t] += sd[t + st];
        __syncthreads();
    }
    if (t == 0) bsum[b] = sd[0];
}

__global__ void scan_bsum(int* __restrict__ bsum, int nb) {
    __shared__ int s[256];
    int t = threadIdx.x;
    int v = (t < nb) ? bsum[t] : 0;
    s[t] = v; __syncthreads();
    for (int st = 1; st < 256; st <<= 1) {
        int add = (t >= st) ? s[t - st] : 0;
        __syncthreads();
        s[t] += add;
        __syncthreads();
    }
    if (t < nb) bsum[t] = s[t] - v;
}

__global__ void scan_final(const int* __restrict__ deg, const int* __restrict__ bsum,
                           int* __restrict__ off, int* __restrict__ pos, int N, int E) {
    __shared__ int ts[256];
    int b = blockIdx.x, t = threadIdx.x, base = b * 1024;
    int v[4], s = 0;
    #pragma unroll
    for (int j = 0; j < 4; ++j) {
        int idx = base + t * 4 + j;
        v[j] = (idx < N) ? deg[idx] : 0;
        s += v[j];
    }
    ts[t] = s; __syncthreads();
    int mine = s;
    for (int st = 1; st < 256; st <<= 1) {
        int add = (t >= st) ? ts[t - st] : 0;
        __syncthreads();
        ts[t] += add;
        __syncthreads();
    }
    int ex = ts[t] - mine + bsum[b];
    #pragma unroll
    for (int j = 0; j < 4; ++j) {
        int idx = base + t * 4 + j;
        if (idx < N) { off[idx] = ex; pos[idx] = ex; }
        ex += v[j];
    }
    if (b == 0 && t == 0) off[N] = E;
}

__global__ void bucket_kernel(const int* __restrict__ src, const int* __restrict__ dst,
                              int* __restrict__ pos, int* __restrict__ eid, int E) {
    int e = blockIdx.x * blockDim.x + threadIdx.x;
    if (e < E) {
        int p = atomicAdd(&pos[dst[e]], 1);
        eid[p] = src[e];
    }
}

// ---------------- aggregate (mean) layer 0: bf16-hi x rows (128 B) ----------------
__global__ __launch_bounds__(256) void aggregate64h(
    const unsigned short* __restrict__ xhi, const int* __restrict__ eid,
    const int* __restrict__ off, float* __restrict__ agg, int N)
{
    int wave = threadIdx.x >> 6, lane = threadIdx.x & 63;
    int n = blockIdx.x * 4 + wave;
    if (n >= N) return;
    int s0 = __builtin_amdgcn_readfirstlane(off[n]);
    int s1 = __builtin_amdgcn_readfirstlane(off[n + 1]);
    float a = 0.0f;
    int i = s0;
    for (; i + 7 < s1; i += 8) {
        float p0 = 0.0f, p1 = 0.0f;
        #pragma unroll
        for (int j = 0; j < 4; ++j) p0 += bf2f(xhi[(size_t)eid[i + j] * 64 + lane]);
        #pragma unroll
        for (int j = 4; j < 8; ++j) p1 += bf2f(xhi[(size_t)eid[i + j] * 64 + lane]);
        a += p0 + p1;
    }
    for (; i < s1; ++i) a += bf2f(xhi[(size_t)eid[i] * 64 + lane]);
    float inv = (s1 > s0) ? 1.0f / (float)(s1 - s0) : 0.0f;
    agg[(size_t)n * 64 + lane] = a * inv;
}

// ---------------- aggregate (mean) layer 1: bf16-hi h rows (256 B) ----------------
__global__ __launch_bounds__(256) void aggregate128h(
    const unsigned short* __restrict__ h_hi, const int* __restrict__ eid,
    const int* __restrict__ off, float* __restrict__ agg, int N)
{
    int wave = threadIdx.x >> 6, lane = threadIdx.x & 63;
    int n = blockIdx.x * 4 + wave;
    if (n >= N) return;
    int s0 = __builtin_amdgcn_readfirstlane(off[n]);
    int s1 = __builtin_amdgcn_readfirstlane(off[n + 1]);
    float ax = 0.0f, ay = 0.0f;
    int i = s0;
    for (; i + 7 < s1; i += 8) {
        ushort2 v[8];
        #pragma unroll
        for (int j = 0; j < 8; ++j)
            v[j] = *(const ushort2*)(h_hi + (size_t)eid[i + j] * 128 + lane * 2);
        #pragma unroll
        for (int j = 0; j < 8; ++j) { ax += bf2f(v[j].x); ay += bf2f(v[j].y); }
    }
    for (; i < s1; ++i) {
        ushort2 va = *(const ushort2*)(h_hi + (size_t)eid[i] * 128 + lane * 2);
        ax += bf2f(va.x); ay += bf2f(va.y);
    }
    float inv = (s1 > s0) ? 1.0f / (float)(s1 - s0) : 0.0f;
    float2 r; r.x = ax * inv; r.y = ay * inv;
    *(float2*)&agg[(size_t)n * 128 + lane * 2] = r;
}

// ---------------- split fp32 -> packed interleaved [hi8|lo8] groups ----------------
__global__ void split_pack(const float* __restrict__ in, unsigned short* __restrict__ outp,
                           int ngroups) {
    int i = blockIdx.x * blockDim.x + threadIdx.x;
    if (i >= ngroups) return;
    float4 a = ((const float4*)in)[i * 2];
    float4 b = ((const float4*)in)[i * 2 + 1];
    float f[8] = {a.x, a.y, a.z, a.w, b.x, b.y, b.z, b.w};
    unsigned short hv[8], lv[8];
    #pragma unroll
    for (int j = 0; j < 8; ++j) {
        unsigned short hb = f2bf(f[j]);
        hv[j] = hb;
        lv[j] = f2bf(f[j] - bf2f(hb));
    }
    ushort4* dst = (ushort4*)(outp + (size_t)i * 16);
    dst[0] = make_ushort4(hv[0], hv[1], hv[2], hv[3]);
    dst[1] = make_ushort4(hv[4], hv[5], hv[6], hv[7]);
    dst[2] = make_ushort4(lv[0], lv[1], lv[2], lv[3]);
    dst[3] = make_ushort4(lv[4], lv[5], lv[6], lv[7]);
}

// ---------------- split x -> packed groups + bf16-hi rows ----------------
__global__ void split_x(const float* __restrict__ in, unsigned short* __restrict__ outp,
                        unsigned short* __restrict__ outh, int ngroups) {
    int i = blockIdx.x * blockDim.x + threadIdx.x;
    if (i >= ngroups) return;
    float4 a = ((const float4*)in)[i * 2];
    float4 b = ((const float4*)in)[i * 2 + 1];
    float f[8] = {a.x, a.y, a.z, a.w, b.x, b.y, b.z, b.w};
    unsigned short hv[8], lv[8];
    #pragma unroll
    for (int j = 0; j < 8; ++j) {
        unsigned short hb = f2bf(f[j]);
        hv[j] = hb;
        lv[j] = f2bf(f[j] - bf2f(hb));
    }
    ushort4* dst = (ushort4*)(outp + (size_t)i * 16);
    dst[0] = make_ushort4(hv[0], hv[1], hv[2], hv[3]);
    dst[1] = make_ushort4(hv[4], hv[5], hv[6], hv[7]);
    dst[2] = make_ushort4(lv[0], lv[1], lv[2], lv[3]);
    dst[3] = make_ushort4(lv[4], lv[5], lv[6], lv[7]);
    ushort4* dh = (ushort4*)(outh + (size_t)i * 8);
    dh[0] = make_ushort4(hv[0], hv[1], hv[2], hv[3]);
    dh[1] = make_ushort4(hv[4], hv[5], hv[6], hv[7]);
}

// ---------------- weight pack: [Wl;Wr] -> fragment-linear [hi8|lo8] ----------------
template<int K0, int K1>
__global__ void wpack(const float* __restrict__ Wl, const float* __restrict__ Wr,
                      unsigned short* __restrict__ outp) {
    int tid = blockIdx.x * blockDim.x + threadIdx.x;
    if (tid >= (K0 + K1) * 128) return;
    int k = tid >> 7, col = tid & 127;
    float v = (k < K0) ? Wl[k * 128 + col] : Wr[(k - K0) * 128 + col];
    int c = k >> 5, ko = k & 31, q = ko >> 3, jj = ko & 7;
    int nt = col >> 4, r = col & 15;
    int base = ((c * 8 + nt) * 64 + (q * 16 + r)) * 16;
    unsigned short hb = f2bf(v);
    outp[base + jj] = hb;
    outp[base + 8 + jj] = f2bf(v - bf2f(hb));
}

__global__ void split_w1(const float* __restrict__ W1, unsigned short* __restrict__ w1p) {
    int tid = blockIdx.x * blockDim.x + threadIdx.x;
    if (tid >= 288 * 128) return;
    int k = tid >> 7, n = tid & 127;
    int c = k >> 5, ko = k & 31, q = ko >> 3, jj = ko & 7;
    int nt = n >> 4, r = n & 15;
    int base = ((c * 8 + nt) * 64 + (q * 16 + r)) * 16;
    float v = W1[tid];
    unsigned short hb = f2bf(v);
    w1p[base + jj] = hb;
    w1p[base + 8 + jj] = f2bf(v - bf2f(hb));
}

// ---------------- SAGE layer GEMM: split-bf16 MFMA ----------------
// Block 256 = 4 waves; tile 64 nodes x 128 cols; wave w -> cols [32w, 32w+32).
// A side (K0): packed [hi8|lo8], 3-pass. X side (K1): XPACK ? packed 3-pass : bf16-hi rows 2-pass.
// Output: bf16-hi linear rows.
template<int K0, int K1, bool RELU, bool XPACK>
__global__ __launch_bounds__(256) void mfma_layer(
    const unsigned short* __restrict__ Ap,
    const unsigned short* __restrict__ Xd,
    const unsigned short* __restrict__ Wp,
    const float* __restrict__ bias,
    unsigned short* __restrict__ outh,
    int N)
{
    __shared__ float buf[4][64 * 36];

    const int t = threadIdx.x, wave = t >> 6, lane = t & 63;
    const int l15 = lane & 15, quad = lane >> 4;
    const int n0 = blockIdx.x * 64;

    f32x4 acc[4][2] = {};

    int nodes[4];
    #pragma unroll
    for (int mt = 0; mt < 4; ++mt) {
        int node = n0 + mt * 16 + l15;
        nodes[mt] = (node < N) ? node : (N - 1);
    }

    // A-side (aggregated) chunks: packed 3-pass
    #pragma unroll
    for (int c = 0; c < K0 / 32; ++c) {
        bf16x8 ah[4], al[4];
        #pragma unroll
        for (int mt = 0; mt < 4; ++mt) {
            const unsigned short* p = Ap + ((size_t)nodes[mt] * (K0 / 8) + c * 4 + quad) * 16;
            ah[mt] = *(const bf16x8*)p;
            al[mt] = *(const bf16x8*)(p + 8);
        }
        #pragma unroll
        for (int ntl = 0; ntl < 2; ++ntl) {
            const int nt = wave * 2 + ntl;
            const unsigned short* wp = Wp + ((size_t)(c * 8 + nt) * 64 + lane) * 16;
            bf16x8 bh = *(const bf16x8*)wp;
            bf16x8 bl = *(const bf16x8*)(wp + 8);
            #pragma unroll
            for (int mt = 0; mt < 4; ++mt) {
                acc[mt][ntl] = __builtin_amdgcn_mfma_f32_16x16x32_bf16(ah[mt], bh, acc[mt][ntl], 0, 0, 0);
                acc[mt][ntl] = __builtin_amdgcn_mfma_f32_16x16x32_bf16(ah[mt], bl, acc[mt][ntl], 0, 0, 0);
                acc[mt][ntl] = __builtin_amdgcn_mfma_f32_16x16x32_bf16(al[mt], bh, acc[mt][ntl], 0, 0, 0);
            }
        }
    }

    // X-side (dense) chunks
    #pragma unroll
    for (int c = 0; c < K1 / 32; ++c) {
        const int cc = K0 / 32 + c;
        bf16x8 ah[4], al[4];
        #pragma unroll
        for (int mt = 0; mt < 4; ++mt) {
            if (XPACK) {
                const unsigned short* p = Xd + ((size_t)nodes[mt] * (K1 / 8) + c * 4 + quad) * 16;
                ah[mt] = *(const bf16x8*)p;
                al[mt] = *(const bf16x8*)(p + 8);
            } else {
                ah[mt] = *(const bf16x8*)(Xd + (size_t)nodes[mt] * K1 + c * 32 + quad * 8);
            }
        }
        #pragma unroll
        for (int ntl = 0; ntl < 2; ++ntl) {
            const int nt = wave * 2 + ntl;
            const unsigned short* wp = Wp + ((size_t)(cc * 8 + nt) * 64 + lane) * 16;
            bf16x8 bh = *(const bf16x8*)wp;
            bf16x8 bl = *(const bf16x8*)(wp + 8);
            #pragma unroll
            for (int mt = 0; mt < 4; ++mt) {
                acc[mt][ntl] = __builtin_amdgcn_mfma_f32_16x16x32_bf16(ah[mt], bh, acc[mt][ntl], 0, 0, 0);
                acc[mt][ntl] = __builtin_amdgcn_mfma_f32_16x16x32_bf16(ah[mt], bl, acc[mt][ntl], 0, 0, 0);
                if (XPACK)
                    acc[mt][ntl] = __builtin_amdgcn_mfma_f32_16x16x32_bf16(al[mt], bh, acc[mt][ntl], 0, 0, 0);
            }
        }
    }

    float bv[2];
    bv[0] = bias[wave * 32 + l15];
    bv[1] = bias[wave * 32 + 16 + l15];

    #pragma unroll
    for (int mt = 0; mt < 4; ++mt)
        #pragma unroll
        for (int ntl = 0; ntl < 2; ++ntl)
            #pragma unroll
            for (int reg = 0; reg < 4; ++reg) {
                int node_l = mt * 16 + quad * 4 + reg;
                int col_l  = ntl * 16 + l15;
                float v = acc[mt][ntl][reg] + bv[ntl];
                if (RELU) v = fmaxf(v, 0.0f);
                buf[wave][node_l * 36 + col_l] = v;
            }
    __syncthreads();

    #pragma unroll
    for (int it = 0; it < 4; ++it) {
        int idx = it * 64 + lane;
        int node_l = idx >> 2, g = idx & 3;
        float4 v0 = *(const float4*)&buf[wave][node_l * 36 + g * 8];
        float4 v1 = *(const float4*)&buf[wave][node_l * 36 + g * 8 + 4];
        float f[8] = {v0.x, v0.y, v0.z, v0.w, v1.x, v1.y, v1.z, v1.w};
        bf16x8 hvv;
        #pragma unroll
        for (int j = 0; j < 8; ++j) hvv[j] = (short)f2bf(f[j]);
        int node_g = n0 + node_l;
        if (node_g < N)
            *(bf16x8*)(outh + (size_t)node_g * 128 + wave * 32 + g * 8) = hvv;
    }
}

// ---------------- classify: bf16-hi A gather (all fragments preloaded), 2-pass B ------
__global__ __launch_bounds__(256, 2) void classify_mfma(
    const unsigned short* __restrict__ h1h,
    const int* __restrict__ fsrc, const int* __restrict__ fdst,
    const float* __restrict__ eattr,
    const unsigned short* __restrict__ w1p,
    const float* __restrict__ b1, const float* __restrict__ W2, const float* __restrict__ b2,
    float* __restrict__ out, int Ef)
{
    __shared__ int es[128], ed[128];

    const int t = threadIdx.x;
    const int wave = t >> 6, lane = t & 63;
    const int l15 = lane & 15, quad = lane >> 4;
    const int e0 = blockIdx.x * 128;

    if (t < 128) {
        int e = e0 + t;
        int ec = (e < Ef) ? e : (Ef - 1);
        es[t] = fsrc[ec];
        ed[t] = fdst[ec];
    }
    __syncthreads();

    const int m0 = wave * 32 + l15;
    int nsrc[2], ndst[2];
    #pragma unroll
    for (int mt = 0; mt < 2; ++mt) {
        nsrc[mt] = es[m0 + mt * 16];
        ndst[mt] = ed[m0 + mt * 16];
    }

    // eattr loads (issued first; conversion deferred to chunk 8)
    float4 ef0[2], ef1[2];
    #pragma unroll
    for (int mt = 0; mt < 2; ++mt) {
        int e = e0 + wave * 32 + mt * 16 + l15;
        if (e >= Ef) e = Ef - 1;
        const float* pe = eattr + (size_t)e * 32 + quad * 8;
        ef0[mt] = *(const float4*)pe;
        ef1[mt] = *(const float4*)(pe + 4);
    }

    // preload ALL A fragments: maximal memory-level parallelism
    bf16x8 a[2][8];
    #pragma unroll
    for (int kc = 0; kc < 8; ++kc)
        #pragma unroll
        for (int mt = 0; mt < 2; ++mt) {
            int node = (kc < 4) ? nsrc[mt] : ndst[mt];
            a[mt][kc] = *(const bf16x8*)(h1h + (size_t)node * 128 + (kc & 3) * 32 + quad * 8);
        }

    f32x4 acc[2][8] = {};

    #pragma unroll
    for (int kc = 0; kc < 8; ++kc) {
        const unsigned short* wp = w1p + ((size_t)(kc * 8) * 64 + lane) * 16;
        #pragma unroll
        for (int nt = 0; nt < 8; ++nt) {
            bf16x8 bh = *(const bf16x8*)(wp + nt * 1024);
            bf16x8 bl = *(const bf16x8*)(wp + nt * 1024 + 8);
            #pragma unroll
            for (int mt = 0; mt < 2; ++mt) {
                acc[mt][nt] = __builtin_amdgcn_mfma_f32_16x16x32_bf16(a[mt][kc], bh, acc[mt][nt], 0, 0, 0);
                acc[mt][nt] = __builtin_amdgcn_mfma_f32_16x16x32_bf16(a[mt][kc], bl, acc[mt][nt], 0, 0, 0);
            }
        }
    }
    {   // chunk 8: eattr
        bf16x8 a8[2];
        #pragma unroll
        for (int mt = 0; mt < 2; ++mt) {
            float fv[8] = {ef0[mt].x, ef0[mt].y, ef0[mt].z, ef0[mt].w,
                           ef1[mt].x, ef1[mt].y, ef1[mt].z, ef1[mt].w};
            #pragma unroll
            for (int j = 0; j < 8; ++j) a8[mt][j] = (short)f2bf(fv[j]);
        }
        const unsigned short* wp = w1p + ((size_t)(8 * 8) * 64 + lane) * 16;
        #pragma unroll
        for (int nt = 0; nt < 8; ++nt) {
            bf16x8 bh = *(const bf16x8*)(wp + nt * 1024);
            bf16x8 bl = *(const bf16x8*)(wp + nt * 1024 + 8);
            #pragma unroll
            for (int mt = 0; mt < 2; ++mt) {
                acc[mt][nt] = __builtin_amdgcn_mfma_f32_16x16x32_bf16(a8[mt], bh, acc[mt][nt], 0, 0, 0);
                acc[mt][nt] = __builtin_amdgcn_mfma_f32_16x16x32_bf16(a8[mt], bl, acc[mt][nt], 0, 0, 0);
            }
        }
    }

    float b1v[8], w2v[8];
    #pragma unroll
    for (int nt = 0; nt < 8; ++nt) {
        b1v[nt] = b1[nt * 16 + l15];
        w2v[nt] = W2[nt * 16 + l15];
    }
    const float b2s = b2[0];

    #pragma unroll
    for (int mt = 0; mt < 2; ++mt) {
        #pragma unroll
        for (int reg = 0; reg < 4; ++reg) {
            float s = 0.0f;
            #pragma unroll
            for (int nt = 0; nt < 8; ++nt) {
                float v = acc[mt][nt][reg] + b1v[nt];
                s += fmaxf(v, 0.0f) * w2v[nt];
            }
            s += __shfl_xor(s, 1);
            s += __shfl_xor(s, 2);
            s += __shfl_xor(s, 4);
            s += __shfl_xor(s, 8);
            if (l15 == 0) {
                int e = e0 + wave * 32 + mt * 16 + quad * 4 + reg;
                if (e < Ef) out[e] = s + b2s;
            }
        }
    }
}

extern "C" void kernel_launch(void* const* d_in, const int* in_sizes, int n_in,
                              void* d_out, int out_size, void* d_ws, size_t ws_size,
                              hipStream_t stream) {
    const float* x     = (const float*)d_in[0];
    const int*   ei    = (const int*)d_in[1];
    const int*   fei   = (const int*)d_in[2];
    const float* eattr = (const float*)d_in[3];
    const float* Wl0   = (const float*)d_in[4];
    const float* bl0   = (const float*)d_in[5];
    const float* Wr0   = (const float*)d_in[6];
    const float* Wl1   = (const float*)d_in[7];
    const float* bl1   = (const float*)d_in[8];
    const float* Wr1   = (const float*)d_in[9];
    const float* W1    = (const float*)d_in[10];
    const float* b1    = (const float*)d_in[11];
    const float* W2    = (const float*)d_in[12];
    const float* b2    = (const float*)d_in[13];

    const int E  = in_sizes[1] / 2;
    const int Ef = in_sizes[2] / 2;
    const int N  = in_sizes[0] / 64;

    const int* src  = ei;
    const int* dst  = ei + E;
    const int* fsrc = fei;
    const int* fdst = fei + Ef;

    // workspace layout (units: floats)
    float* wsf = (float*)d_ws;
    size_t o = 0;
    int* deg  = (int*)(wsf + o); o += 131072;
    int* off  = (int*)(wsf + o); o += 131072;
    int* pos  = (int*)(wsf + o); o += 131072;
    int* bsum = (int*)(wsf + o); o += 256;
    int* eid  = (int*)(wsf + o); o += 1 << 20;
    unsigned short* w0p = (unsigned short*)(wsf + o); o += 16384;
    unsigned short* wLp = (unsigned short*)(wsf + o); o += 32768;
    unsigned short* w1p = (unsigned short*)(wsf + o); o += 36864;
    unsigned short* xp  = (unsigned short*)(wsf + o); o += (size_t)N * 64;   // packed x (N*8 groups)
    unsigned short* xhi = (unsigned short*)(wsf + o); o += (size_t)N * 32;   // bf16-hi x rows
    float* agg          = wsf + o;                    o += (size_t)N * 128;  // fp32 agg scratch
    unsigned short* aggp= (unsigned short*)(wsf + o); o += (size_t)N * 128;  // packed agg

    // overlays (phase-disjoint / block-local lifetimes):
    unsigned short* h_hi  = xp;                   // written by mfma_layer0 epilogue (block-local rows)
    unsigned short* h1_hi = (unsigned short*)agg; // agg dead after second split_pack
    float* out = (float*)d_out;

    const int nb = (N + 1023) / 1024;

    hipMemsetAsync(deg, 0, (size_t)N * 4, stream);
    degree_kernel<<<(E + 255) / 256, 256, 0, stream>>>(dst, deg, E);
    scan_reduce<<<nb, 256, 0, stream>>>(deg, bsum, N);
    scan_bsum<<<1, 256, 0, stream>>>(bsum, nb);
    scan_final<<<nb, 256, 0, stream>>>(deg, bsum, off, pos, N, E);
    bucket_kernel<<<(E + 255) / 256, 256, 0, stream>>>(src, dst, pos, eid, E);

    wpack<64, 64><<<(128 * 128 + 255) / 256, 256, 0, stream>>>(Wl0, Wr0, w0p);
    wpack<128, 128><<<(256 * 128 + 255) / 256, 256, 0, stream>>>(Wl1, Wr1, wLp);
    split_w1<<<(288 * 128 + 255) / 256, 256, 0, stream>>>(W1, w1p);

    split_x<<<((N * 8) + 255) / 256, 256, 0, stream>>>(x, xp, xhi, N * 8);

    aggregate64h<<<(N + 3) / 4, 256, 0, stream>>>(xhi, eid, off, agg, N);
    split_pack<<<((N * 8) + 255) / 256, 256, 0, stream>>>(agg, aggp, N * 8);
    mfma_layer<64, 64, true, true><<<(N + 63) / 64, 256, 0, stream>>>(
        aggp, xp, w0p, bl0, h_hi, N);

    aggregate128h<<<(N + 3) / 4, 256, 0, stream>>>(h_hi, eid, off, agg, N);
    split_pack<<<((N * 16) + 255) / 256, 256, 0, stream>>>(agg, aggp, N * 16);
    mfma_layer<128, 128, false, false><<<(N + 63) / 64, 256, 0, stream>>>(
        aggp, h_hi, wLp, bl1, h1_hi, N);

    classify_mfma<<<(Ef + 127) / 128, 256, 0, stream>>>(
        h1_hi, fsrc, fdst, eattr, w1p, b1, W2, b2, out, Ef);
}

// Round 9
// 546.265 us; speedup vs baseline: 1.4189x; 1.0054x over previous
//
#include <hip/hip_runtime.h>

typedef __attribute__((ext_vector_type(8))) short bf16x8;
typedef __attribute__((ext_vector_type(4))) float f32x4;

__device__ inline unsigned short f2bf(float f) {
    unsigned u = __float_as_uint(f);
    unsigned r = (u + 0x7FFF + ((u >> 16) & 1)) >> 16;   // RNE
    return (unsigned short)r;
}
__device__ inline float bf2f(unsigned short h) { return __uint_as_float((unsigned)h << 16); }

// ---------------- CSR build ----------------
__global__ void degree_kernel(const int* __restrict__ dst, int* __restrict__ deg, int E) {
    int e = blockIdx.x * blockDim.x + threadIdx.x;
    if (e < E) atomicAdd(&deg[dst[e]], 1);
}

__global__ void scan_reduce(const int* __restrict__ deg, int* __restrict__ bsum, int N) {
    __shared__ int sd[256];
    int b = blockIdx.x, t = threadIdx.x;
    int base = b * 1024, s = 0;
    for (int i = t; i < 1024; i += 256) {
        int idx = base + i;
        s += (idx < N) ? deg[idx] : 0;
    }
    sd[t] = s; __syncthreads();
    for (int st = 128; st > 0; st >>= 1) {
        if (t < st) sd[t] += sd[t + st];
        __syncthreads();
    }
    if (t == 0) bsum[b] = sd[0];
}

__global__ void scan_bsum(int* __restrict__ bsum, int nb) {
    __shared__ int s[256];
    int t = threadIdx.x;
    int v = (t < nb) ? bsum[t] : 0;
    s[t] = v; __syncthreads();
    for (int st = 1; st < 256; st <<= 1) {
        int add = (t >= st) ? s[t - st] : 0;
        __syncthreads();
        s[t] += add;
        __syncthreads();
    }
    if (t < nb) bsum[t] = s[t] - v;
}

__global__ void scan_final(const int* __restrict__ deg, const int* __restrict__ bsum,
                           int* __restrict__ off, int* __restrict__ pos, int N, int E) {
    __shared__ int ts[256];
    int b = blockIdx.x, t = threadIdx.x, base = b * 1024;
    int v[4], s = 0;
    #pragma unroll
    for (int j = 0; j < 4; ++j) {
        int idx = base + t * 4 + j;
        v[j] = (idx < N) ? deg[idx] : 0;
        s += v[j];
    }
    ts[t] = s; __syncthreads();
    int mine = s;
    for (int st = 1; st < 256; st <<= 1) {
        int add = (t >= st) ? ts[t - st] : 0;
        __syncthreads();
        ts[t] += add;
        __syncthreads();
    }
    int ex = ts[t] - mine + bsum[b];
    #pragma unroll
    for (int j = 0; j < 4; ++j) {
        int idx = base + t * 4 + j;
        if (idx < N) { off[idx] = ex; pos[idx] = ex; }
        ex += v[j];
    }
    if (b == 0 && t == 0) off[N] = E;
}

__global__ void bucket_kernel(const int* __restrict__ src, const int* __restrict__ dst,
                              int* __restrict__ pos, int* __restrict__ eid, int E) {
    int e = blockIdx.x * blockDim.x + threadIdx.x;
    if (e < E) {
        int p = atomicAdd(&pos[dst[e]], 1);
        eid[p] = src[e];
    }
}

// ---------------- aggregate (mean) layer 0: bf16-hi x rows (128 B) ----------------
__global__ __launch_bounds__(256) void aggregate64h(
    const unsigned short* __restrict__ xhi, const int* __restrict__ eid,
    const int* __restrict__ off, float* __restrict__ agg, int N)
{
    int wave = threadIdx.x >> 6, lane = threadIdx.x & 63;
    int n = blockIdx.x * 4 + wave;
    if (n >= N) return;
    int s0 = __builtin_amdgcn_readfirstlane(off[n]);
    int s1 = __builtin_amdgcn_readfirstlane(off[n + 1]);
    float a = 0.0f;
    int i = s0;
    for (; i + 7 < s1; i += 8) {
        float p0 = 0.0f, p1 = 0.0f;
        #pragma unroll
        for (int j = 0; j < 4; ++j) p0 += bf2f(xhi[(size_t)eid[i + j] * 64 + lane]);
        #pragma unroll
        for (int j = 4; j < 8; ++j) p1 += bf2f(xhi[(size_t)eid[i + j] * 64 + lane]);
        a += p0 + p1;
    }
    for (; i < s1; ++i) a += bf2f(xhi[(size_t)eid[i] * 64 + lane]);
    float inv = (s1 > s0) ? 1.0f / (float)(s1 - s0) : 0.0f;
    agg[(size_t)n * 64 + lane] = a * inv;
}

// ---------------- aggregate (mean) layer 1: bf16-hi h rows (256 B) ----------------
__global__ __launch_bounds__(256) void aggregate128h(
    const unsigned short* __restrict__ h_hi, const int* __restrict__ eid,
    const int* __restrict__ off, float* __restrict__ agg, int N)
{
    int wave = threadIdx.x >> 6, lane = threadIdx.x & 63;
    int n = blockIdx.x * 4 + wave;
    if (n >= N) return;
    int s0 = __builtin_amdgcn_readfirstlane(off[n]);
    int s1 = __builtin_amdgcn_readfirstlane(off[n + 1]);
    float ax = 0.0f, ay = 0.0f;
    int i = s0;
    for (; i + 7 < s1; i += 8) {
        ushort2 v[8];
        #pragma unroll
        for (int j = 0; j < 8; ++j)
            v[j] = *(const ushort2*)(h_hi + (size_t)eid[i + j] * 128 + lane * 2);
        #pragma unroll
        for (int j = 0; j < 8; ++j) { ax += bf2f(v[j].x); ay += bf2f(v[j].y); }
    }
    for (; i < s1; ++i) {
        ushort2 va = *(const ushort2*)(h_hi + (size_t)eid[i] * 128 + lane * 2);
        ax += bf2f(va.x); ay += bf2f(va.y);
    }
    float inv = (s1 > s0) ? 1.0f / (float)(s1 - s0) : 0.0f;
    float2 r; r.x = ax * inv; r.y = ay * inv;
    *(float2*)&agg[(size_t)n * 128 + lane * 2] = r;
}

// ---------------- split fp32 -> packed interleaved [hi8|lo8] groups ----------------
__global__ void split_pack(const float* __restrict__ in, unsigned short* __restrict__ outp,
                           int ngroups) {
    int i = blockIdx.x * blockDim.x + threadIdx.x;
    if (i >= ngroups) return;
    float4 a = ((const float4*)in)[i * 2];
    float4 b = ((const float4*)in)[i * 2 + 1];
    float f[8] = {a.x, a.y, a.z, a.w, b.x, b.y, b.z, b.w};
    unsigned short hv[8], lv[8];
    #pragma unroll
    for (int j = 0; j < 8; ++j) {
        unsigned short hb = f2bf(f[j]);
        hv[j] = hb;
        lv[j] = f2bf(f[j] - bf2f(hb));
    }
    ushort4* dst = (ushort4*)(outp + (size_t)i * 16);
    dst[0] = make_ushort4(hv[0], hv[1], hv[2], hv[3]);
    dst[1] = make_ushort4(hv[4], hv[5], hv[6], hv[7]);
    dst[2] = make_ushort4(lv[0], lv[1], lv[2], lv[3]);
    dst[3] = make_ushort4(lv[4], lv[5], lv[6], lv[7]);
}

// ---------------- split x -> packed groups + bf16-hi rows ----------------
__global__ void split_x(const float* __restrict__ in, unsigned short* __restrict__ outp,
                        unsigned short* __restrict__ outh, int ngroups) {
    int i = blockIdx.x * blockDim.x + threadIdx.x;
    if (i >= ngroups) return;
    float4 a = ((const float4*)in)[i * 2];
    float4 b = ((const float4*)in)[i * 2 + 1];
    float f[8] = {a.x, a.y, a.z, a.w, b.x, b.y, b.z, b.w};
    unsigned short hv[8], lv[8];
    #pragma unroll
    for (int j = 0; j < 8; ++j) {
        unsigned short hb = f2bf(f[j]);
        hv[j] = hb;
        lv[j] = f2bf(f[j] - bf2f(hb));
    }
    ushort4* dst = (ushort4*)(outp + (size_t)i * 16);
    dst[0] = make_ushort4(hv[0], hv[1], hv[2], hv[3]);
    dst[1] = make_ushort4(hv[4], hv[5], hv[6], hv[7]);
    dst[2] = make_ushort4(lv[0], lv[1], lv[2], lv[3]);
    dst[3] = make_ushort4(lv[4], lv[5], lv[6], lv[7]);
    ushort4* dh = (ushort4*)(outh + (size_t)i * 8);
    dh[0] = make_ushort4(hv[0], hv[1], hv[2], hv[3]);
    dh[1] = make_ushort4(hv[4], hv[5], hv[6], hv[7]);
}

// ---------------- weight pack: [Wl;Wr] -> fragment-linear [hi8|lo8] ----------------
template<int K0, int K1>
__global__ void wpack(const float* __restrict__ Wl, const float* __restrict__ Wr,
                      unsigned short* __restrict__ outp) {
    int tid = blockIdx.x * blockDim.x + threadIdx.x;
    if (tid >= (K0 + K1) * 128) return;
    int k = tid >> 7, col = tid & 127;
    float v = (k < K0) ? Wl[k * 128 + col] : Wr[(k - K0) * 128 + col];
    int c = k >> 5, ko = k & 31, q = ko >> 3, jj = ko & 7;
    int nt = col >> 4, r = col & 15;
    int base = ((c * 8 + nt) * 64 + (q * 16 + r)) * 16;
    unsigned short hb = f2bf(v);
    outp[base + jj] = hb;
    outp[base + 8 + jj] = f2bf(v - bf2f(hb));
}

__global__ void split_w1(const float* __restrict__ W1, unsigned short* __restrict__ w1p) {
    int tid = blockIdx.x * blockDim.x + threadIdx.x;
    if (tid >= 288 * 128) return;
    int k = tid >> 7, n = tid & 127;
    int c = k >> 5, ko = k & 31, q = ko >> 3, jj = ko & 7;
    int nt = n >> 4, r = n & 15;
    int base = ((c * 8 + nt) * 64 + (q * 16 + r)) * 16;
    float v = W1[tid];
    unsigned short hb = f2bf(v);
    w1p[base + jj] = hb;
    w1p[base + 8 + jj] = f2bf(v - bf2f(hb));
}

// ---------------- SAGE layer GEMM: split-bf16 MFMA ----------------
template<int K0, int K1, bool RELU, bool XPACK>
__global__ __launch_bounds__(256) void mfma_layer(
    const unsigned short* __restrict__ Ap,
    const unsigned short* __restrict__ Xd,
    const unsigned short* __restrict__ Wp,
    const float* __restrict__ bias,
    unsigned short* __restrict__ outh,
    int N)
{
    __shared__ float buf[4][64 * 36];

    const int t = threadIdx.x, wave = t >> 6, lane = t & 63;
    const int l15 = lane & 15, quad = lane >> 4;
    const int n0 = blockIdx.x * 64;

    f32x4 acc[4][2] = {};

    int nodes[4];
    #pragma unroll
    for (int mt = 0; mt < 4; ++mt) {
        int node = n0 + mt * 16 + l15;
        nodes[mt] = (node < N) ? node : (N - 1);
    }

    #pragma unroll
    for (int c = 0; c < K0 / 32; ++c) {
        bf16x8 ah[4], al[4];
        #pragma unroll
        for (int mt = 0; mt < 4; ++mt) {
            const unsigned short* p = Ap + ((size_t)nodes[mt] * (K0 / 8) + c * 4 + quad) * 16;
            ah[mt] = *(const bf16x8*)p;
            al[mt] = *(const bf16x8*)(p + 8);
        }
        #pragma unroll
        for (int ntl = 0; ntl < 2; ++ntl) {
            const int nt = wave * 2 + ntl;
            const unsigned short* wp = Wp + ((size_t)(c * 8 + nt) * 64 + lane) * 16;
            bf16x8 bh = *(const bf16x8*)wp;
            bf16x8 bl = *(const bf16x8*)(wp + 8);
            #pragma unroll
            for (int mt = 0; mt < 4; ++mt) {
                acc[mt][ntl] = __builtin_amdgcn_mfma_f32_16x16x32_bf16(ah[mt], bh, acc[mt][ntl], 0, 0, 0);
                acc[mt][ntl] = __builtin_amdgcn_mfma_f32_16x16x32_bf16(ah[mt], bl, acc[mt][ntl], 0, 0, 0);
                acc[mt][ntl] = __builtin_amdgcn_mfma_f32_16x16x32_bf16(al[mt], bh, acc[mt][ntl], 0, 0, 0);
            }
        }
    }

    #pragma unroll
    for (int c = 0; c < K1 / 32; ++c) {
        const int cc = K0 / 32 + c;
        bf16x8 ah[4], al[4];
        #pragma unroll
        for (int mt = 0; mt < 4; ++mt) {
            if (XPACK) {
                const unsigned short* p = Xd + ((size_t)nodes[mt] * (K1 / 8) + c * 4 + quad) * 16;
                ah[mt] = *(const bf16x8*)p;
                al[mt] = *(const bf16x8*)(p + 8);
            } else {
                ah[mt] = *(const bf16x8*)(Xd + (size_t)nodes[mt] * K1 + c * 32 + quad * 8);
            }
        }
        #pragma unroll
        for (int ntl = 0; ntl < 2; ++ntl) {
            const int nt = wave * 2 + ntl;
            const unsigned short* wp = Wp + ((size_t)(cc * 8 + nt) * 64 + lane) * 16;
            bf16x8 bh = *(const bf16x8*)wp;
            bf16x8 bl = *(const bf16x8*)(wp + 8);
            #pragma unroll
            for (int mt = 0; mt < 4; ++mt) {
                acc[mt][ntl] = __builtin_amdgcn_mfma_f32_16x16x32_bf16(ah[mt], bh, acc[mt][ntl], 0, 0, 0);
                acc[mt][ntl] = __builtin_amdgcn_mfma_f32_16x16x32_bf16(ah[mt], bl, acc[mt][ntl], 0, 0, 0);
                if (XPACK)
                    acc[mt][ntl] = __builtin_amdgcn_mfma_f32_16x16x32_bf16(al[mt], bh, acc[mt][ntl], 0, 0, 0);
            }
        }
    }

    float bv[2];
    bv[0] = bias[wave * 32 + l15];
    bv[1] = bias[wave * 32 + 16 + l15];

    #pragma unroll
    for (int mt = 0; mt < 4; ++mt)
        #pragma unroll
        for (int ntl = 0; ntl < 2; ++ntl)
            #pragma unroll
            for (int reg = 0; reg < 4; ++reg) {
                int node_l = mt * 16 + quad * 4 + reg;
                int col_l  = ntl * 16 + l15;
                float v = acc[mt][ntl][reg] + bv[ntl];
                if (RELU) v = fmaxf(v, 0.0f);
                buf[wave][node_l * 36 + col_l] = v;
            }
    __syncthreads();

    #pragma unroll
    for (int it = 0; it < 4; ++it) {
        int idx = it * 64 + lane;
        int node_l = idx >> 2, g = idx & 3;
        float4 v0 = *(const float4*)&buf[wave][node_l * 36 + g * 8];
        float4 v1 = *(const float4*)&buf[wave][node_l * 36 + g * 8 + 4];
        float f[8] = {v0.x, v0.y, v0.z, v0.w, v1.x, v1.y, v1.z, v1.w};
        bf16x8 hvv;
        #pragma unroll
        for (int j = 0; j < 8; ++j) hvv[j] = (short)f2bf(f[j]);
        int node_g = n0 + node_l;
        if (node_g < N)
            *(bf16x8*)(outh + (size_t)node_g * 128 + wave * 32 + g * 8) = hvv;
    }
}

// ---------------- classify: preloaded A + 8-deep software-pipelined B FIFO ----------
// Flat pair index p = kc*8+nt in [0,72), pair address = w1p + p*1024 + lane*16.
__global__ __launch_bounds__(256, 2) void classify_mfma(
    const unsigned short* __restrict__ h1h,
    const int* __restrict__ fsrc, const int* __restrict__ fdst,
    const float* __restrict__ eattr,
    const unsigned short* __restrict__ w1p,
    const float* __restrict__ b1, const float* __restrict__ W2, const float* __restrict__ b2,
    float* __restrict__ out, int Ef)
{
    __shared__ int es[128], ed[128];

    const int t = threadIdx.x;
    const int wave = t >> 6, lane = t & 63;
    const int l15 = lane & 15, quad = lane >> 4;
    const int e0 = blockIdx.x * 128;

    if (t < 128) {
        int e = e0 + t;
        int ec = (e < Ef) ? e : (Ef - 1);
        es[t] = fsrc[ec];
        ed[t] = fdst[ec];
    }
    __syncthreads();

    const int m0 = wave * 32 + l15;
    int nsrc[2], ndst[2];
    #pragma unroll
    for (int mt = 0; mt < 2; ++mt) {
        nsrc[mt] = es[m0 + mt * 16];
        ndst[mt] = ed[m0 + mt * 16];
    }

    // eattr loads (issued early)
    float4 ef0[2], ef1[2];
    #pragma unroll
    for (int mt = 0; mt < 2; ++mt) {
        int e = e0 + wave * 32 + mt * 16 + l15;
        if (e >= Ef) e = Ef - 1;
        const float* pe = eattr + (size_t)e * 32 + quad * 8;
        ef0[mt] = *(const float4*)pe;
        ef1[mt] = *(const float4*)(pe + 4);
    }

    // preload ALL h1 A fragments (16 gathers in flight)
    bf16x8 a[2][8];
    #pragma unroll
    for (int kc = 0; kc < 8; ++kc)
        #pragma unroll
        for (int mt = 0; mt < 2; ++mt) {
            int node = (kc < 4) ? nsrc[mt] : ndst[mt];
            a[mt][kc] = *(const bf16x8*)(h1h + (size_t)node * 128 + (kc & 3) * 32 + quad * 8);
        }

    // B FIFO prime: pairs 0..7
    const unsigned short* wbase = w1p + (size_t)lane * 16;
    bf16x8 bhb[8], blb[8];
    #pragma unroll
    for (int p = 0; p < 8; ++p) {
        bhb[p] = *(const bf16x8*)(wbase + (size_t)p * 1024);
        blb[p] = *(const bf16x8*)(wbase + (size_t)p * 1024 + 8);
    }

    // eattr -> bf16 fragments (chunk 8)
    bf16x8 a8[2];
    #pragma unroll
    for (int mt = 0; mt < 2; ++mt) {
        float fv[8] = {ef0[mt].x, ef0[mt].y, ef0[mt].z, ef0[mt].w,
                       ef1[mt].x, ef1[mt].y, ef1[mt].z, ef1[mt].w};
        #pragma unroll
        for (int j = 0; j < 8; ++j) a8[mt][j] = (short)f2bf(fv[j]);
    }

    f32x4 acc[2][8] = {};

    #pragma unroll
    for (int p = 0; p < 72; ++p) {          // 9 chunks x 8 nt = 72 pairs (K=288)
        const int kc = p >> 3, nt = p & 7, slot = p & 7;
        bf16x8 bh = bhb[slot], bl = blb[slot];
        if (p + 8 < 72) {
            bhb[slot] = *(const bf16x8*)(wbase + (size_t)(p + 8) * 1024);
            blb[slot] = *(const bf16x8*)(wbase + (size_t)(p + 8) * 1024 + 8);
        }
        bf16x8 a0 = (kc < 8) ? a[0][kc] : a8[0];
        bf16x8 a1 = (kc < 8) ? a[1][kc] : a8[1];
        acc[0][nt] = __builtin_amdgcn_mfma_f32_16x16x32_bf16(a0, bh, acc[0][nt], 0, 0, 0);
        acc[0][nt] = __builtin_amdgcn_mfma_f32_16x16x32_bf16(a0, bl, acc[0][nt], 0, 0, 0);
        acc[1][nt] = __builtin_amdgcn_mfma_f32_16x16x32_bf16(a1, bh, acc[1][nt], 0, 0, 0);
        acc[1][nt] = __builtin_amdgcn_mfma_f32_16x16x32_bf16(a1, bl, acc[1][nt], 0, 0, 0);
    }

    float b1v[8], w2v[8];
    #pragma unroll
    for (int nt = 0; nt < 8; ++nt) {
        b1v[nt] = b1[nt * 16 + l15];
        w2v[nt] = W2[nt * 16 + l15];
    }
    const float b2s = b2[0];

    #pragma unroll
    for (int mt = 0; mt < 2; ++mt) {
        #pragma unroll
        for (int reg = 0; reg < 4; ++reg) {
            float s = 0.0f;
            #pragma unroll
            for (int nt = 0; nt < 8; ++nt) {
                float v = acc[mt][nt][reg] + b1v[nt];
                s += fmaxf(v, 0.0f) * w2v[nt];
            }
            s += __shfl_xor(s, 1);
            s += __shfl_xor(s, 2);
            s += __shfl_xor(s, 4);
            s += __shfl_xor(s, 8);
            if (l15 == 0) {
                int e = e0 + wave * 32 + mt * 16 + quad * 4 + reg;
                if (e < Ef) out[e] = s + b2s;
            }
        }
    }
}

extern "C" void kernel_launch(void* const* d_in, const int* in_sizes, int n_in,
                              void* d_out, int out_size, void* d_ws, size_t ws_size,
                              hipStream_t stream) {
    const float* x     = (const float*)d_in[0];
    const int*   ei    = (const int*)d_in[1];
    const int*   fei   = (const int*)d_in[2];
    const float* eattr = (const float*)d_in[3];
    const float* Wl0   = (const float*)d_in[4];
    const float* bl0   = (const float*)d_in[5];
    const float* Wr0   = (const float*)d_in[6];
    const float* Wl1   = (const float*)d_in[7];
    const float* bl1   = (const float*)d_in[8];
    const float* Wr1   = (const float*)d_in[9];
    const float* W1    = (const float*)d_in[10];
    const float* b1    = (const float*)d_in[11];
    const float* W2    = (const float*)d_in[12];
    const float* b2    = (const float*)d_in[13];

    const int E  = in_sizes[1] / 2;
    const int Ef = in_sizes[2] / 2;
    const int N  = in_sizes[0] / 64;

    const int* src  = ei;
    const int* dst  = ei + E;
    const int* fsrc = fei;
    const int* fdst = fei + Ef;

    // workspace layout (units: floats)
    float* wsf = (float*)d_ws;
    size_t o = 0;
    int* deg  = (int*)(wsf + o); o += 131072;
    int* off  = (int*)(wsf + o); o += 131072;
    int* pos  = (int*)(wsf + o); o += 131072;
    int* bsum = (int*)(wsf + o); o += 256;
    int* eid  = (int*)(wsf + o); o += 1 << 20;
    unsigned short* w0p = (unsigned short*)(wsf + o); o += 16384;
    unsigned short* wLp = (unsigned short*)(wsf + o); o += 32768;
    unsigned short* w1p = (unsigned short*)(wsf + o); o += 36864;
    unsigned short* xp  = (unsigned short*)(wsf + o); o += (size_t)N * 64;   // packed x
    unsigned short* xhi = (unsigned short*)(wsf + o); o += (size_t)N * 32;   // bf16-hi x rows
    float* agg          = wsf + o;                    o += (size_t)N * 128;  // fp32 agg scratch
    unsigned short* aggp= (unsigned short*)(wsf + o); o += (size_t)N * 128;  // packed agg

    unsigned short* h_hi  = xp;                   // overlay: block-local rows
    unsigned short* h1_hi = (unsigned short*)agg; // overlay: agg dead after second split_pack
    float* out = (float*)d_out;

    const int nb = (N + 1023) / 1024;

    hipMemsetAsync(deg, 0, (size_t)N * 4, stream);
    degree_kernel<<<(E + 255) / 256, 256, 0, stream>>>(dst, deg, E);
    scan_reduce<<<nb, 256, 0, stream>>>(deg, bsum, N);
    scan_bsum<<<1, 256, 0, stream>>>(bsum, nb);
    scan_final<<<nb, 256, 0, stream>>>(deg, bsum, off, pos, N, E);
    bucket_kernel<<<(E + 255) / 256, 256, 0, stream>>>(src, dst, pos, eid, E);

    wpack<64, 64><<<(128 * 128 + 255) / 256, 256, 0, stream>>>(Wl0, Wr0, w0p);
    wpack<128, 128><<<(256 * 128 + 255) / 256, 256, 0, stream>>>(Wl1, Wr1, wLp);
    split_w1<<<(288 * 128 + 255) / 256, 256, 0, stream>>>(W1, w1p);

    split_x<<<((N * 8) + 255) / 256, 256, 0, stream>>>(x, xp, xhi, N * 8);

    aggregate64h<<<(N + 3) / 4, 256, 0, stream>>>(xhi, eid, off, agg, N);
    split_pack<<<((N * 8) + 255) / 256, 256, 0, stream>>>(agg, aggp, N * 8);
    mfma_layer<64, 64, true, true><<<(N + 63) / 64, 256, 0, stream>>>(
        aggp, xp, w0p, bl0, h_hi, N);

    aggregate128h<<<(N + 3) / 4, 256, 0, stream>>>(h_hi, eid, off, agg, N);
    split_pack<<<((N * 16) + 255) / 256, 256, 0, stream>>>(agg, aggp, N * 16);
    mfma_layer<128, 128, false, false><<<(N + 63) / 64, 256, 0, stream>>>(
        aggp, h_hi, wLp, bl1, h1_hi, N);

    classify_mfma<<<(Ef + 127) / 128, 256, 0, stream>>>(
        h1_hi, fsrc, fdst, eattr, w1p, b1, W2, b2, out, Ef);
}

// Round 10
// 508.549 us; speedup vs baseline: 1.5241x; 1.0742x over previous
//
#include <hip/hip_runtime.h>

typedef __attribute__((ext_vector_type(8))) short bf16x8;
typedef __attribute__((ext_vector_type(4))) float f32x4;

__device__ inline unsigned short f2bf(float f) {
    unsigned u = __float_as_uint(f);
    unsigned r = (u + 0x7FFF + ((u >> 16) & 1)) >> 16;   // RNE
    return (unsigned short)r;
}
__device__ inline float bf2f(unsigned short h) { return __uint_as_float((unsigned)h << 16); }

// ---------------- CSR build ----------------
__global__ void degree_kernel(const int* __restrict__ dst, int* __restrict__ deg, int E) {
    int e = blockIdx.x * blockDim.x + threadIdx.x;
    if (e < E) atomicAdd(&deg[dst[e]], 1);
}

__global__ void scan_reduce(const int* __restrict__ deg, int* __restrict__ bsum, int N) {
    __shared__ int sd[256];
    int b = blockIdx.x, t = threadIdx.x;
    int base = b * 1024, s = 0;
    for (int i = t; i < 1024; i += 256) {
        int idx = base + i;
        s += (idx < N) ? deg[idx] : 0;
    }
    sd[t] = s; __syncthreads();
    for (int st = 128; st > 0; st >>= 1) {
        if (t < st) sd[t] += sd[t + st];
        __syncthreads();
    }
    if (t == 0) bsum[b] = sd[0];
}

__global__ void scan_bsum(int* __restrict__ bsum, int nb) {
    __shared__ int s[256];
    int t = threadIdx.x;
    int v = (t < nb) ? bsum[t] : 0;
    s[t] = v; __syncthreads();
    for (int st = 1; st < 256; st <<= 1) {
        int add = (t >= st) ? s[t - st] : 0;
        __syncthreads();
        s[t] += add;
        __syncthreads();
    }
    if (t < nb) bsum[t] = s[t] - v;
}

__global__ void scan_final(const int* __restrict__ deg, const int* __restrict__ bsum,
                           int* __restrict__ off, int* __restrict__ pos, int N, int E) {
    __shared__ int ts[256];
    int b = blockIdx.x, t = threadIdx.x, base = b * 1024;
    int v[4], s = 0;
    #pragma unroll
    for (int j = 0; j < 4; ++j) {
        int idx = base + t * 4 + j;
        v[j] = (idx < N) ? deg[idx] : 0;
        s += v[j];
    }
    ts[t] = s; __syncthreads();
    int mine = s;
    for (int st = 1; st < 256; st <<= 1) {
        int add = (t >= st) ? ts[t - st] : 0;
        __syncthreads();
        ts[t] += add;
        __syncthreads();
    }
    int ex = ts[t] - mine + bsum[b];
    #pragma unroll
    for (int j = 0; j < 4; ++j) {
        int idx = base + t * 4 + j;
        if (idx < N) { off[idx] = ex; pos[idx] = ex; }
        ex += v[j];
    }
    if (b == 0 && t == 0) off[N] = E;
}

__global__ void bucket_kernel(const int* __restrict__ src, const int* __restrict__ dst,
                              int* __restrict__ pos, int* __restrict__ eid, int E) {
    int e = blockIdx.x * blockDim.x + threadIdx.x;
    if (e < E) {
        int p = atomicAdd(&pos[dst[e]], 1);
        eid[p] = src[e];
    }
}

// ---------------- aggregate (mean) layer 0: bf16-hi x rows (128 B) ----------------
__global__ __launch_bounds__(256) void aggregate64h(
    const unsigned short* __restrict__ xhi, const int* __restrict__ eid,
    const int* __restrict__ off, float* __restrict__ agg, int N)
{
    int wave = threadIdx.x >> 6, lane = threadIdx.x & 63;
    int n = blockIdx.x * 4 + wave;
    if (n >= N) return;
    int s0 = __builtin_amdgcn_readfirstlane(off[n]);
    int s1 = __builtin_amdgcn_readfirstlane(off[n + 1]);
    float a = 0.0f;
    int i = s0;
    for (; i + 7 < s1; i += 8) {
        float p0 = 0.0f, p1 = 0.0f;
        #pragma unroll
        for (int j = 0; j < 4; ++j) p0 += bf2f(xhi[(size_t)eid[i + j] * 64 + lane]);
        #pragma unroll
        for (int j = 4; j < 8; ++j) p1 += bf2f(xhi[(size_t)eid[i + j] * 64 + lane]);
        a += p0 + p1;
    }
    for (; i < s1; ++i) a += bf2f(xhi[(size_t)eid[i] * 64 + lane]);
    float inv = (s1 > s0) ? 1.0f / (float)(s1 - s0) : 0.0f;
    agg[(size_t)n * 64 + lane] = a * inv;
}

// ---------------- aggregate (mean) layer 1: bf16-hi h rows (256 B) ----------------
__global__ __launch_bounds__(256) void aggregate128h(
    const unsigned short* __restrict__ h_hi, const int* __restrict__ eid,
    const int* __restrict__ off, float* __restrict__ agg, int N)
{
    int wave = threadIdx.x >> 6, lane = threadIdx.x & 63;
    int n = blockIdx.x * 4 + wave;
    if (n >= N) return;
    int s0 = __builtin_amdgcn_readfirstlane(off[n]);
    int s1 = __builtin_amdgcn_readfirstlane(off[n + 1]);
    float ax = 0.0f, ay = 0.0f;
    int i = s0;
    for (; i + 7 < s1; i += 8) {
        ushort2 v[8];
        #pragma unroll
        for (int j = 0; j < 8; ++j)
            v[j] = *(const ushort2*)(h_hi + (size_t)eid[i + j] * 128 + lane * 2);
        #pragma unroll
        for (int j = 0; j < 8; ++j) { ax += bf2f(v[j].x); ay += bf2f(v[j].y); }
    }
    for (; i < s1; ++i) {
        ushort2 va = *(const ushort2*)(h_hi + (size_t)eid[i] * 128 + lane * 2);
        ax += bf2f(va.x); ay += bf2f(va.y);
    }
    float inv = (s1 > s0) ? 1.0f / (float)(s1 - s0) : 0.0f;
    float2 r; r.x = ax * inv; r.y = ay * inv;
    *(float2*)&agg[(size_t)n * 128 + lane * 2] = r;
}

// ---------------- split fp32 -> packed interleaved [hi8|lo8] groups ----------------
__global__ void split_pack(const float* __restrict__ in, unsigned short* __restrict__ outp,
                           int ngroups) {
    int i = blockIdx.x * blockDim.x + threadIdx.x;
    if (i >= ngroups) return;
    float4 a = ((const float4*)in)[i * 2];
    float4 b = ((const float4*)in)[i * 2 + 1];
    float f[8] = {a.x, a.y, a.z, a.w, b.x, b.y, b.z, b.w};
    unsigned short hv[8], lv[8];
    #pragma unroll
    for (int j = 0; j < 8; ++j) {
        unsigned short hb = f2bf(f[j]);
        hv[j] = hb;
        lv[j] = f2bf(f[j] - bf2f(hb));
    }
    ushort4* dst = (ushort4*)(outp + (size_t)i * 16);
    dst[0] = make_ushort4(hv[0], hv[1], hv[2], hv[3]);
    dst[1] = make_ushort4(hv[4], hv[5], hv[6], hv[7]);
    dst[2] = make_ushort4(lv[0], lv[1], lv[2], lv[3]);
    dst[3] = make_ushort4(lv[4], lv[5], lv[6], lv[7]);
}

// ---------------- split x -> packed groups + bf16-hi rows ----------------
__global__ void split_x(const float* __restrict__ in, unsigned short* __restrict__ outp,
                        unsigned short* __restrict__ outh, int ngroups) {
    int i = blockIdx.x * blockDim.x + threadIdx.x;
    if (i >= ngroups) return;
    float4 a = ((const float4*)in)[i * 2];
    float4 b = ((const float4*)in)[i * 2 + 1];
    float f[8] = {a.x, a.y, a.z, a.w, b.x, b.y, b.z, b.w};
    unsigned short hv[8], lv[8];
    #pragma unroll
    for (int j = 0; j < 8; ++j) {
        unsigned short hb = f2bf(f[j]);
        hv[j] = hb;
        lv[j] = f2bf(f[j] - bf2f(hb));
    }
    ushort4* dst = (ushort4*)(outp + (size_t)i * 16);
    dst[0] = make_ushort4(hv[0], hv[1], hv[2], hv[3]);
    dst[1] = make_ushort4(hv[4], hv[5], hv[6], hv[7]);
    dst[2] = make_ushort4(lv[0], lv[1], lv[2], lv[3]);
    dst[3] = make_ushort4(lv[4], lv[5], lv[6], lv[7]);
    ushort4* dh = (ushort4*)(outh + (size_t)i * 8);
    dh[0] = make_ushort4(hv[0], hv[1], hv[2], hv[3]);
    dh[1] = make_ushort4(hv[4], hv[5], hv[6], hv[7]);
}

// ---------------- weight pack: [Wl;Wr] -> fragment-linear [hi8|lo8] ----------------
template<int K0, int K1>
__global__ void wpack(const float* __restrict__ Wl, const float* __restrict__ Wr,
                      unsigned short* __restrict__ outp) {
    int tid = blockIdx.x * blockDim.x + threadIdx.x;
    if (tid >= (K0 + K1) * 128) return;
    int k = tid >> 7, col = tid & 127;
    float v = (k < K0) ? Wl[k * 128 + col] : Wr[(k - K0) * 128 + col];
    int c = k >> 5, ko = k & 31, q = ko >> 3, jj = ko & 7;
    int nt = col >> 4, r = col & 15;
    int base = ((c * 8 + nt) * 64 + (q * 16 + r)) * 16;
    unsigned short hb = f2bf(v);
    outp[base + jj] = hb;
    outp[base + 8 + jj] = f2bf(v - bf2f(hb));
}

// W1 (288x128) -> fragment-linear bf16-hi ONLY (classify single-pass B)
__global__ void split_w1h(const float* __restrict__ W1, unsigned short* __restrict__ w1h) {
    int tid = blockIdx.x * blockDim.x + threadIdx.x;
    if (tid >= 288 * 128) return;
    int k = tid >> 7, n = tid & 127;
    int c = k >> 5, ko = k & 31, q = ko >> 3, jj = ko & 7;
    int nt = n >> 4, r = n & 15;
    int base = ((c * 8 + nt) * 64 + (q * 16 + r)) * 8;
    w1h[base + jj] = f2bf(W1[tid]);
}

// ---------------- SAGE layer GEMM: split-bf16 MFMA ----------------
template<int K0, int K1, bool RELU, bool XPACK>
__global__ __launch_bounds__(256) void mfma_layer(
    const unsigned short* __restrict__ Ap,
    const unsigned short* __restrict__ Xd,
    const unsigned short* __restrict__ Wp,
    const float* __restrict__ bias,
    unsigned short* __restrict__ outh,
    int N)
{
    __shared__ float buf[4][64 * 36];

    const int t = threadIdx.x, wave = t >> 6, lane = t & 63;
    const int l15 = lane & 15, quad = lane >> 4;
    const int n0 = blockIdx.x * 64;

    f32x4 acc[4][2] = {};

    int nodes[4];
    #pragma unroll
    for (int mt = 0; mt < 4; ++mt) {
        int node = n0 + mt * 16 + l15;
        nodes[mt] = (node < N) ? node : (N - 1);
    }

    #pragma unroll
    for (int c = 0; c < K0 / 32; ++c) {
        bf16x8 ah[4], al[4];
        #pragma unroll
        for (int mt = 0; mt < 4; ++mt) {
            const unsigned short* p = Ap + ((size_t)nodes[mt] * (K0 / 8) + c * 4 + quad) * 16;
            ah[mt] = *(const bf16x8*)p;
            al[mt] = *(const bf16x8*)(p + 8);
        }
        #pragma unroll
        for (int ntl = 0; ntl < 2; ++ntl) {
            const int nt = wave * 2 + ntl;
            const unsigned short* wp = Wp + ((size_t)(c * 8 + nt) * 64 + lane) * 16;
            bf16x8 bh = *(const bf16x8*)wp;
            bf16x8 bl = *(const bf16x8*)(wp + 8);
            #pragma unroll
            for (int mt = 0; mt < 4; ++mt) {
                acc[mt][ntl] = __builtin_amdgcn_mfma_f32_16x16x32_bf16(ah[mt], bh, acc[mt][ntl], 0, 0, 0);
                acc[mt][ntl] = __builtin_amdgcn_mfma_f32_16x16x32_bf16(ah[mt], bl, acc[mt][ntl], 0, 0, 0);
                acc[mt][ntl] = __builtin_amdgcn_mfma_f32_16x16x32_bf16(al[mt], bh, acc[mt][ntl], 0, 0, 0);
            }
        }
    }

    #pragma unroll
    for (int c = 0; c < K1 / 32; ++c) {
        const int cc = K0 / 32 + c;
        bf16x8 ah[4], al[4];
        #pragma unroll
        for (int mt = 0; mt < 4; ++mt) {
            if (XPACK) {
                const unsigned short* p = Xd + ((size_t)nodes[mt] * (K1 / 8) + c * 4 + quad) * 16;
                ah[mt] = *(const bf16x8*)p;
                al[mt] = *(const bf16x8*)(p + 8);
            } else {
                ah[mt] = *(const bf16x8*)(Xd + (size_t)nodes[mt] * K1 + c * 32 + quad * 8);
            }
        }
        #pragma unroll
        for (int ntl = 0; ntl < 2; ++ntl) {
            const int nt = wave * 2 + ntl;
            const unsigned short* wp = Wp + ((size_t)(cc * 8 + nt) * 64 + lane) * 16;
            bf16x8 bh = *(const bf16x8*)wp;
            bf16x8 bl = *(const bf16x8*)(wp + 8);
            #pragma unroll
            for (int mt = 0; mt < 4; ++mt) {
                acc[mt][ntl] = __builtin_amdgcn_mfma_f32_16x16x32_bf16(ah[mt], bh, acc[mt][ntl], 0, 0, 0);
                acc[mt][ntl] = __builtin_amdgcn_mfma_f32_16x16x32_bf16(ah[mt], bl, acc[mt][ntl], 0, 0, 0);
                if (XPACK)
                    acc[mt][ntl] = __builtin_amdgcn_mfma_f32_16x16x32_bf16(al[mt], bh, acc[mt][ntl], 0, 0, 0);
            }
        }
    }

    float bv[2];
    bv[0] = bias[wave * 32 + l15];
    bv[1] = bias[wave * 32 + 16 + l15];

    #pragma unroll
    for (int mt = 0; mt < 4; ++mt)
        #pragma unroll
        for (int ntl = 0; ntl < 2; ++ntl)
            #pragma unroll
            for (int reg = 0; reg < 4; ++reg) {
                int node_l = mt * 16 + quad * 4 + reg;
                int col_l  = ntl * 16 + l15;
                float v = acc[mt][ntl][reg] + bv[ntl];
                if (RELU) v = fmaxf(v, 0.0f);
                buf[wave][node_l * 36 + col_l] = v;
            }
    __syncthreads();

    #pragma unroll
    for (int it = 0; it < 4; ++it) {
        int idx = it * 64 + lane;
        int node_l = idx >> 2, g = idx & 3;
        float4 v0 = *(const float4*)&buf[wave][node_l * 36 + g * 8];
        float4 v1 = *(const float4*)&buf[wave][node_l * 36 + g * 8 + 4];
        float f[8] = {v0.x, v0.y, v0.z, v0.w, v1.x, v1.y, v1.z, v1.w};
        bf16x8 hvv;
        #pragma unroll
        for (int j = 0; j < 8; ++j) hvv[j] = (short)f2bf(f[j]);
        int node_g = n0 + node_l;
        if (node_g < N)
            *(bf16x8*)(outh + (size_t)node_g * 128 + wave * 32 + g * 8) = hvv;
    }
}

// ---------------- classify: bf16-hi A gather + bf16-hi single-pass B ----------------
// Flat pair p = kc*8+nt in [0,72): B at w1h + p*512 + lane*8 (512 B per pair per wave).
__global__ __launch_bounds__(256, 3) void classify_mfma(
    const unsigned short* __restrict__ h1h,
    const int* __restrict__ fsrc, const int* __restrict__ fdst,
    const float* __restrict__ eattr,
    const unsigned short* __restrict__ w1h,
    const float* __restrict__ b1, const float* __restrict__ W2, const float* __restrict__ b2,
    float* __restrict__ out, int Ef)
{
    __shared__ int es[128], ed[128];

    const int t = threadIdx.x;
    const int wave = t >> 6, lane = t & 63;
    const int l15 = lane & 15, quad = lane >> 4;
    const int e0 = blockIdx.x * 128;

    if (t < 128) {
        int e = e0 + t;
        int ec = (e < Ef) ? e : (Ef - 1);
        es[t] = fsrc[ec];
        ed[t] = fdst[ec];
    }
    __syncthreads();

    const int m0 = wave * 32 + l15;
    int nsrc[2], ndst[2];
    #pragma unroll
    for (int mt = 0; mt < 2; ++mt) {
        nsrc[mt] = es[m0 + mt * 16];
        ndst[mt] = ed[m0 + mt * 16];
    }

    // eattr loads (issued early)
    float4 ef0[2], ef1[2];
    #pragma unroll
    for (int mt = 0; mt < 2; ++mt) {
        int e = e0 + wave * 32 + mt * 16 + l15;
        if (e >= Ef) e = Ef - 1;
        const float* pe = eattr + (size_t)e * 32 + quad * 8;
        ef0[mt] = *(const float4*)pe;
        ef1[mt] = *(const float4*)(pe + 4);
    }

    // preload ALL h1 A fragments (16 gathers in flight)
    bf16x8 a[2][8];
    #pragma unroll
    for (int kc = 0; kc < 8; ++kc)
        #pragma unroll
        for (int mt = 0; mt < 2; ++mt) {
            int node = (kc < 4) ? nsrc[mt] : ndst[mt];
            a[mt][kc] = *(const bf16x8*)(h1h + (size_t)node * 128 + (kc & 3) * 32 + quad * 8);
        }

    // B FIFO prime: pairs 0..7 (hi only)
    const unsigned short* wbase = w1h + (size_t)lane * 8;
    bf16x8 bhb[8];
    #pragma unroll
    for (int p = 0; p < 8; ++p)
        bhb[p] = *(const bf16x8*)(wbase + (size_t)p * 512);

    // eattr -> bf16 fragments (chunk 8)
    bf16x8 a8[2];
    #pragma unroll
    for (int mt = 0; mt < 2; ++mt) {
        float fv[8] = {ef0[mt].x, ef0[mt].y, ef0[mt].z, ef0[mt].w,
                       ef1[mt].x, ef1[mt].y, ef1[mt].z, ef1[mt].w};
        #pragma unroll
        for (int j = 0; j < 8; ++j) a8[mt][j] = (short)f2bf(fv[j]);
    }

    f32x4 acc[2][8] = {};

    #pragma unroll
    for (int p = 0; p < 72; ++p) {          // 9 chunks x 8 nt = 72 pairs (K=288)
        const int kc = p >> 3, nt = p & 7, slot = p & 7;
        bf16x8 bh = bhb[slot];
        if (p + 8 < 72)
            bhb[slot] = *(const bf16x8*)(wbase + (size_t)(p + 8) * 512);
        bf16x8 a0 = (kc < 8) ? a[0][kc] : a8[0];
        bf16x8 a1 = (kc < 8) ? a[1][kc] : a8[1];
        acc[0][nt] = __builtin_amdgcn_mfma_f32_16x16x32_bf16(a0, bh, acc[0][nt], 0, 0, 0);
        acc[1][nt] = __builtin_amdgcn_mfma_f32_16x16x32_bf16(a1, bh, acc[1][nt], 0, 0, 0);
    }

    float b1v[8], w2v[8];
    #pragma unroll
    for (int nt = 0; nt < 8; ++nt) {
        b1v[nt] = b1[nt * 16 + l15];
        w2v[nt] = W2[nt * 16 + l15];
    }
    const float b2s = b2[0];

    #pragma unroll
    for (int mt = 0; mt < 2; ++mt) {
        #pragma unroll
        for (int reg = 0; reg < 4; ++reg) {
            float s = 0.0f;
            #pragma unroll
            for (int nt = 0; nt < 8; ++nt) {
                float v = acc[mt][nt][reg] + b1v[nt];
                s += fmaxf(v, 0.0f) * w2v[nt];
            }
            s += __shfl_xor(s, 1);
            s += __shfl_xor(s, 2);
            s += __shfl_xor(s, 4);
            s += __shfl_xor(s, 8);
            if (l15 == 0) {
                int e = e0 + wave * 32 + mt * 16 + quad * 4 + reg;
                if (e < Ef) out[e] = s + b2s;
            }
        }
    }
}

extern "C" void kernel_launch(void* const* d_in, const int* in_sizes, int n_in,
                              void* d_out, int out_size, void* d_ws, size_t ws_size,
                              hipStream_t stream) {
    const float* x     = (const float*)d_in[0];
    const int*   ei    = (const int*)d_in[1];
    const int*   fei   = (const int*)d_in[2];
    const float* eattr = (const float*)d_in[3];
    const float* Wl0   = (const float*)d_in[4];
    const float* bl0   = (const float*)d_in[5];
    const float* Wr0   = (const float*)d_in[6];
    const float* Wl1   = (const float*)d_in[7];
    const float* bl1   = (const float*)d_in[8];
    const float* Wr1   = (const float*)d_in[9];
    const float* W1    = (const float*)d_in[10];
    const float* b1    = (const float*)d_in[11];
    const float* W2    = (const float*)d_in[12];
    const float* b2    = (const float*)d_in[13];

    const int E  = in_sizes[1] / 2;
    const int Ef = in_sizes[2] / 2;
    const int N  = in_sizes[0] / 64;

    const int* src  = ei;
    const int* dst  = ei + E;
    const int* fsrc = fei;
    const int* fdst = fei + Ef;

    // workspace layout (units: floats)
    float* wsf = (float*)d_ws;
    size_t o = 0;
    int* deg  = (int*)(wsf + o); o += 131072;
    int* off  = (int*)(wsf + o); o += 131072;
    int* pos  = (int*)(wsf + o); o += 131072;
    int* bsum = (int*)(wsf + o); o += 256;
    int* eid  = (int*)(wsf + o); o += 1 << 20;
    unsigned short* w0p = (unsigned short*)(wsf + o); o += 16384;
    unsigned short* wLp = (unsigned short*)(wsf + o); o += 32768;
    unsigned short* w1h = (unsigned short*)(wsf + o); o += 18432;   // 288*128 bf16-hi
    unsigned short* xp  = (unsigned short*)(wsf + o); o += (size_t)N * 64;   // packed x
    unsigned short* xhi = (unsigned short*)(wsf + o); o += (size_t)N * 32;   // bf16-hi x rows
    float* agg          = wsf + o;                    o += (size_t)N * 128;  // fp32 agg scratch
    unsigned short* aggp= (unsigned short*)(wsf + o); o += (size_t)N * 128;  // packed agg

    unsigned short* h_hi  = xp;                   // overlay: block-local rows
    unsigned short* h1_hi = (unsigned short*)agg; // overlay: agg dead after second split_pack
    float* out = (float*)d_out;

    const int nb = (N + 1023) / 1024;

    hipMemsetAsync(deg, 0, (size_t)N * 4, stream);
    degree_kernel<<<(E + 255) / 256, 256, 0, stream>>>(dst, deg, E);
    scan_reduce<<<nb, 256, 0, stream>>>(deg, bsum, N);
    scan_bsum<<<1, 256, 0, stream>>>(bsum, nb);
    scan_final<<<nb, 256, 0, stream>>>(deg, bsum, off, pos, N, E);
    bucket_kernel<<<(E + 255) / 256, 256, 0, stream>>>(src, dst, pos, eid, E);

    wpack<64, 64><<<(128 * 128 + 255) / 256, 256, 0, stream>>>(Wl0, Wr0, w0p);
    wpack<128, 128><<<(256 * 128 + 255) / 256, 256, 0, stream>>>(Wl1, Wr1, wLp);
    split_w1h<<<(288 * 128 + 255) / 256, 256, 0, stream>>>(W1, w1h);

    split_x<<<((N * 8) + 255) / 256, 256, 0, stream>>>(x, xp, xhi, N * 8);

    aggregate64h<<<(N + 3) / 4, 256, 0, stream>>>(xhi, eid, off, agg, N);
    split_pack<<<((N * 8) + 255) / 256, 256, 0, stream>>>(agg, aggp, N * 8);
    mfma_layer<64, 64, true, true><<<(N + 63) / 64, 256, 0, stream>>>(
        aggp, xp, w0p, bl0, h_hi, N);

    aggregate128h<<<(N + 3) / 4, 256, 0, stream>>>(h_hi, eid, off, agg, N);
    split_pack<<<((N * 16) + 255) / 256, 256, 0, stream>>>(agg, aggp, N * 16);
    mfma_layer<128, 128, false, false><<<(N + 63) / 64, 256, 0, stream>>>(
        aggp, h_hi, wLp, bl1, h1_hi, N);

    classify_mfma<<<(Ef + 127) / 128, 256, 0, stream>>>(
        h1_hi, fsrc, fdst, eattr, w1h, b1, W2, b2, out, Ef);
}

// Round 11
// 457.073 us; speedup vs baseline: 1.6957x; 1.1126x over previous
//
#include <hip/hip_runtime.h>

typedef __attribute__((ext_vector_type(8))) short bf16x8;
typedef __attribute__((ext_vector_type(4))) float f32x4;

__device__ inline unsigned short f2bf(float f) {
    unsigned u = __float_as_uint(f);
    unsigned r = (u + 0x7FFF + ((u >> 16) & 1)) >> 16;   // RNE
    return (unsigned short)r;
}
__device__ inline float bf2f(unsigned short h) { return __uint_as_float((unsigned)h << 16); }

// ---------------- CSR build ----------------
__global__ void degree_kernel(const int* __restrict__ dst, int* __restrict__ deg, int E) {
    int e = blockIdx.x * blockDim.x + threadIdx.x;
    if (e < E) atomicAdd(&deg[dst[e]], 1);
}

__global__ void scan_reduce(const int* __restrict__ deg, int* __restrict__ bsum, int N) {
    __shared__ int sd[256];
    int b = blockIdx.x, t = threadIdx.x;
    int base = b * 1024, s = 0;
    for (int i = t; i < 1024; i += 256) {
        int idx = base + i;
        s += (idx < N) ? deg[idx] : 0;
    }
    sd[t] = s; __syncthreads();
    for (int st = 128; st > 0; st >>= 1) {
        if (t < st) sd[t] += sd[t + st];
        __syncthreads();
    }
    if (t == 0) bsum[b] = sd[0];
}

__global__ void scan_bsum(int* __restrict__ bsum, int nb) {
    __shared__ int s[256];
    int t = threadIdx.x;
    int v = (t < nb) ? bsum[t] : 0;
    s[t] = v; __syncthreads();
    for (int st = 1; st < 256; st <<= 1) {
        int add = (t >= st) ? s[t - st] : 0;
        __syncthreads();
        s[t] += add;
        __syncthreads();
    }
    if (t < nb) bsum[t] = s[t] - v;
}

__global__ void scan_final(const int* __restrict__ deg, const int* __restrict__ bsum,
                           int* __restrict__ off, int* __restrict__ pos, int N, int E) {
    __shared__ int ts[256];
    int b = blockIdx.x, t = threadIdx.x, base = b * 1024;
    int v[4], s = 0;
    #pragma unroll
    for (int j = 0; j < 4; ++j) {
        int idx = base + t * 4 + j;
        v[j] = (idx < N) ? deg[idx] : 0;
        s += v[j];
    }
    ts[t] = s; __syncthreads();
    int mine = s;
    for (int st = 1; st < 256; st <<= 1) {
        int add = (t >= st) ? ts[t - st] : 0;
        __syncthreads();
        ts[t] += add;
        __syncthreads();
    }
    int ex = ts[t] - mine + bsum[b];
    #pragma unroll
    for (int j = 0; j < 4; ++j) {
        int idx = base + t * 4 + j;
        if (idx < N) { off[idx] = ex; pos[idx] = ex; }
        ex += v[j];
    }
    if (b == 0 && t == 0) off[N] = E;
}

__global__ void bucket_kernel(const int* __restrict__ src, const int* __restrict__ dst,
                              int* __restrict__ pos, int* __restrict__ eid, int E) {
    int e = blockIdx.x * blockDim.x + threadIdx.x;
    if (e < E) {
        int p = atomicAdd(&pos[dst[e]], 1);
        eid[p] = src[e];
    }
}

// ---------------- aggregate (mean) layer 0: bf16-hi x rows -> packed out ----------------
__global__ __launch_bounds__(256) void aggregate64p(
    const unsigned short* __restrict__ xhi, const int* __restrict__ eid,
    const int* __restrict__ off, unsigned short* __restrict__ aggp, int N)
{
    int wave = threadIdx.x >> 6, lane = threadIdx.x & 63;
    int n = blockIdx.x * 4 + wave;
    if (n >= N) return;
    int s0 = __builtin_amdgcn_readfirstlane(off[n]);
    int s1 = __builtin_amdgcn_readfirstlane(off[n + 1]);
    float a = 0.0f;
    int i = s0;
    for (; i + 7 < s1; i += 8) {
        float p0 = 0.0f, p1 = 0.0f;
        #pragma unroll
        for (int j = 0; j < 4; ++j) p0 += bf2f(xhi[(size_t)eid[i + j] * 64 + lane]);
        #pragma unroll
        for (int j = 4; j < 8; ++j) p1 += bf2f(xhi[(size_t)eid[i + j] * 64 + lane]);
        a += p0 + p1;
    }
    for (; i < s1; ++i) a += bf2f(xhi[(size_t)eid[i] * 64 + lane]);
    float inv = (s1 > s0) ? 1.0f / (float)(s1 - s0) : 0.0f;
    float m = a * inv;
    unsigned short hb = f2bf(m);
    unsigned short lb = f2bf(m - bf2f(hb));
    int g = lane >> 3, p = lane & 7;
    unsigned short* row = aggp + (size_t)n * 128;
    row[g * 16 + p]     = hb;
    row[g * 16 + 8 + p] = lb;
}

// ---------------- aggregate (mean) layer 1: bf16-hi h rows -> packed out ----------------
__global__ __launch_bounds__(256) void aggregate128p(
    const unsigned short* __restrict__ h_hi, const int* __restrict__ eid,
    const int* __restrict__ off, unsigned short* __restrict__ aggp, int N)
{
    int wave = threadIdx.x >> 6, lane = threadIdx.x & 63;
    int n = blockIdx.x * 4 + wave;
    if (n >= N) return;
    int s0 = __builtin_amdgcn_readfirstlane(off[n]);
    int s1 = __builtin_amdgcn_readfirstlane(off[n + 1]);
    float ax = 0.0f, ay = 0.0f;
    int i = s0;
    for (; i + 7 < s1; i += 8) {
        ushort2 v[8];
        #pragma unroll
        for (int j = 0; j < 8; ++j)
            v[j] = *(const ushort2*)(h_hi + (size_t)eid[i + j] * 128 + lane * 2);
        #pragma unroll
        for (int j = 0; j < 8; ++j) { ax += bf2f(v[j].x); ay += bf2f(v[j].y); }
    }
    for (; i < s1; ++i) {
        ushort2 va = *(const ushort2*)(h_hi + (size_t)eid[i] * 128 + lane * 2);
        ax += bf2f(va.x); ay += bf2f(va.y);
    }
    float inv = (s1 > s0) ? 1.0f / (float)(s1 - s0) : 0.0f;
    float mx = ax * inv, my = ay * inv;
    ushort2 h2, l2;
    h2.x = f2bf(mx); l2.x = f2bf(mx - bf2f(h2.x));
    h2.y = f2bf(my); l2.y = f2bf(my - bf2f(h2.y));
    int g = lane >> 2, p0 = (lane & 3) * 2;
    unsigned short* row = aggp + (size_t)n * 256;
    *(ushort2*)&row[g * 16 + p0]     = h2;
    *(ushort2*)&row[g * 16 + 8 + p0] = l2;
}

// ---------------- split x -> packed groups + bf16-hi rows ----------------
__global__ void split_x(const float* __restrict__ in, unsigned short* __restrict__ outp,
                        unsigned short* __restrict__ outh, int ngroups) {
    int i = blockIdx.x * blockDim.x + threadIdx.x;
    if (i >= ngroups) return;
    float4 a = ((const float4*)in)[i * 2];
    float4 b = ((const float4*)in)[i * 2 + 1];
    float f[8] = {a.x, a.y, a.z, a.w, b.x, b.y, b.z, b.w};
    unsigned short hv[8], lv[8];
    #pragma unroll
    for (int j = 0; j < 8; ++j) {
        unsigned short hb = f2bf(f[j]);
        hv[j] = hb;
        lv[j] = f2bf(f[j] - bf2f(hb));
    }
    ushort4* dst = (ushort4*)(outp + (size_t)i * 16);
    dst[0] = make_ushort4(hv[0], hv[1], hv[2], hv[3]);
    dst[1] = make_ushort4(hv[4], hv[5], hv[6], hv[7]);
    dst[2] = make_ushort4(lv[0], lv[1], lv[2], lv[3]);
    dst[3] = make_ushort4(lv[4], lv[5], lv[6], lv[7]);
    ushort4* dh = (ushort4*)(outh + (size_t)i * 8);
    dh[0] = make_ushort4(hv[0], hv[1], hv[2], hv[3]);
    dh[1] = make_ushort4(hv[4], hv[5], hv[6], hv[7]);
}

// ---------------- all weight packs in one kernel ----------------
__device__ inline void pack16(unsigned short* outp, int k, int col, float v) {
    int c = k >> 5, ko = k & 31, q = ko >> 3, jj = ko & 7;
    int nt = col >> 4, r = col & 15;
    int base = ((c * 8 + nt) * 64 + (q * 16 + r)) * 16;
    unsigned short hb = f2bf(v);
    outp[base + jj] = hb;
    outp[base + 8 + jj] = f2bf(v - bf2f(hb));
}

__global__ void pack_weights(const float* __restrict__ Wl0, const float* __restrict__ Wr0,
                             const float* __restrict__ Wl1, const float* __restrict__ Wr1,
                             const float* __restrict__ W1,
                             unsigned short* __restrict__ w0p, unsigned short* __restrict__ wLp,
                             unsigned short* __restrict__ w1h) {
    int tid = blockIdx.x * blockDim.x + threadIdx.x;
    if (tid < 16384) {                       // layer0: K=128
        int k = tid >> 7, col = tid & 127;
        float v = (k < 64) ? Wl0[k * 128 + col] : Wr0[(k - 64) * 128 + col];
        pack16(w0p, k, col, v);
    } else if (tid < 49152) {                // layer1: K=256
        int t2 = tid - 16384;
        int k = t2 >> 7, col = t2 & 127;
        float v = (k < 128) ? Wl1[k * 128 + col] : Wr1[(k - 128) * 128 + col];
        pack16(wLp, k, col, v);
    } else if (tid < 86016) {                // W1: K=288, hi only
        int t2 = tid - 49152;
        int k = t2 >> 7, col = t2 & 127;
        int c = k >> 5, ko = k & 31, q = ko >> 3, jj = ko & 7;
        int nt = col >> 4, r = col & 15;
        w1h[((c * 8 + nt) * 64 + q * 16 + r) * 8 + jj] = f2bf(W1[t2]);
    }
}

// ---------------- SAGE layer GEMM: split-bf16 MFMA ----------------
template<int K0, int K1, bool RELU, bool XPACK>
__global__ __launch_bounds__(256) void mfma_layer(
    const unsigned short* __restrict__ Ap,
    const unsigned short* __restrict__ Xd,
    const unsigned short* __restrict__ Wp,
    const float* __restrict__ bias,
    unsigned short* __restrict__ outh,
    int N)
{
    __shared__ float buf[4][64 * 36];

    const int t = threadIdx.x, wave = t >> 6, lane = t & 63;
    const int l15 = lane & 15, quad = lane >> 4;
    const int n0 = blockIdx.x * 64;

    f32x4 acc[4][2] = {};

    int nodes[4];
    #pragma unroll
    for (int mt = 0; mt < 4; ++mt) {
        int node = n0 + mt * 16 + l15;
        nodes[mt] = (node < N) ? node : (N - 1);
    }

    #pragma unroll
    for (int c = 0; c < K0 / 32; ++c) {
        bf16x8 ah[4], al[4];
        #pragma unroll
        for (int mt = 0; mt < 4; ++mt) {
            const unsigned short* p = Ap + ((size_t)nodes[mt] * (K0 / 8) + c * 4 + quad) * 16;
            ah[mt] = *(const bf16x8*)p;
            al[mt] = *(const bf16x8*)(p + 8);
        }
        #pragma unroll
        for (int ntl = 0; ntl < 2; ++ntl) {
            const int nt = wave * 2 + ntl;
            const unsigned short* wp = Wp + ((size_t)(c * 8 + nt) * 64 + lane) * 16;
            bf16x8 bh = *(const bf16x8*)wp;
            bf16x8 bl = *(const bf16x8*)(wp + 8);
            #pragma unroll
            for (int mt = 0; mt < 4; ++mt) {
                acc[mt][ntl] = __builtin_amdgcn_mfma_f32_16x16x32_bf16(ah[mt], bh, acc[mt][ntl], 0, 0, 0);
                acc[mt][ntl] = __builtin_amdgcn_mfma_f32_16x16x32_bf16(ah[mt], bl, acc[mt][ntl], 0, 0, 0);
                acc[mt][ntl] = __builtin_amdgcn_mfma_f32_16x16x32_bf16(al[mt], bh, acc[mt][ntl], 0, 0, 0);
            }
        }
    }

    #pragma unroll
    for (int c = 0; c < K1 / 32; ++c) {
        const int cc = K0 / 32 + c;
        bf16x8 ah[4], al[4];
        #pragma unroll
        for (int mt = 0; mt < 4; ++mt) {
            if (XPACK) {
                const unsigned short* p = Xd + ((size_t)nodes[mt] * (K1 / 8) + c * 4 + quad) * 16;
                ah[mt] = *(const bf16x8*)p;
                al[mt] = *(const bf16x8*)(p + 8);
            } else {
                ah[mt] = *(const bf16x8*)(Xd + (size_t)nodes[mt] * K1 + c * 32 + quad * 8);
            }
        }
        #pragma unroll
        for (int ntl = 0; ntl < 2; ++ntl) {
            const int nt = wave * 2 + ntl;
            const unsigned short* wp = Wp + ((size_t)(cc * 8 + nt) * 64 + lane) * 16;
            bf16x8 bh = *(const bf16x8*)wp;
            bf16x8 bl = *(const bf16x8*)(wp + 8);
            #pragma unroll
            for (int mt = 0; mt < 4; ++mt) {
                acc[mt][ntl] = __builtin_amdgcn_mfma_f32_16x16x32_bf16(ah[mt], bh, acc[mt][ntl], 0, 0, 0);
                acc[mt][ntl] = __builtin_amdgcn_mfma_f32_16x16x32_bf16(ah[mt], bl, acc[mt][ntl], 0, 0, 0);
                if (XPACK)
                    acc[mt][ntl] = __builtin_amdgcn_mfma_f32_16x16x32_bf16(al[mt], bh, acc[mt][ntl], 0, 0, 0);
            }
        }
    }

    float bv[2];
    bv[0] = bias[wave * 32 + l15];
    bv[1] = bias[wave * 32 + 16 + l15];

    #pragma unroll
    for (int mt = 0; mt < 4; ++mt)
        #pragma unroll
        for (int ntl = 0; ntl < 2; ++ntl)
            #pragma unroll
            for (int reg = 0; reg < 4; ++reg) {
                int node_l = mt * 16 + quad * 4 + reg;
                int col_l  = ntl * 16 + l15;
                float v = acc[mt][ntl][reg] + bv[ntl];
                if (RELU) v = fmaxf(v, 0.0f);
                buf[wave][node_l * 36 + col_l] = v;
            }
    __syncthreads();

    #pragma unroll
    for (int it = 0; it < 4; ++it) {
        int idx = it * 64 + lane;
        int node_l = idx >> 2, g = idx & 3;
        float4 v0 = *(const float4*)&buf[wave][node_l * 36 + g * 8];
        float4 v1 = *(const float4*)&buf[wave][node_l * 36 + g * 8 + 4];
        float f[8] = {v0.x, v0.y, v0.z, v0.w, v1.x, v1.y, v1.z, v1.w};
        bf16x8 hvv;
        #pragma unroll
        for (int j = 0; j < 8; ++j) hvv[j] = (short)f2bf(f[j]);
        int node_g = n0 + node_l;
        if (node_g < N)
            *(bf16x8*)(outh + (size_t)node_g * 128 + wave * 32 + g * 8) = hvv;
    }
}

// ---------------- classify: LDS-staged B (60 pairs) + reg tail (12) + preloaded A ----
__global__ __launch_bounds__(256, 2) void classify_mfma(
    const unsigned short* __restrict__ h1h,
    const int* __restrict__ fsrc, const int* __restrict__ fdst,
    const float* __restrict__ eattr,
    const unsigned short* __restrict__ w1h,
    const float* __restrict__ b1, const float* __restrict__ W2, const float* __restrict__ b2,
    float* __restrict__ out, int Ef)
{
    __shared__ unsigned short wlds[60 * 512];   // 60 pairs x 1 KB = 61440 B

    const int t = threadIdx.x;
    const int wave = t >> 6, lane = t & 63;
    const int l15 = lane & 15, quad = lane >> 4;
    const int e0 = blockIdx.x * 128;

    // stage first 60 B pairs into LDS (3840 uint4 = 15/thread)
    {
        const uint4* s4 = (const uint4*)w1h;
        uint4* d4 = (uint4*)wlds;
        #pragma unroll
        for (int i = 0; i < 15; ++i)
            d4[t + i * 256] = s4[t + i * 256];
    }

    // per-lane edge indices (no LDS needed)
    int nsrc[2], ndst[2];
    #pragma unroll
    for (int mt = 0; mt < 2; ++mt) {
        int e = e0 + wave * 32 + mt * 16 + l15;
        if (e >= Ef) e = Ef - 1;
        nsrc[mt] = fsrc[e];
        ndst[mt] = fdst[e];
    }

    // eattr loads (issued early)
    float4 ef0[2], ef1[2];
    #pragma unroll
    for (int mt = 0; mt < 2; ++mt) {
        int e = e0 + wave * 32 + mt * 16 + l15;
        if (e >= Ef) e = Ef - 1;
        const float* pe = eattr + (size_t)e * 32 + quad * 8;
        ef0[mt] = *(const float4*)pe;
        ef1[mt] = *(const float4*)(pe + 4);
    }

    // preload ALL h1 A fragments (16 gathers in flight)
    bf16x8 a[2][8];
    #pragma unroll
    for (int kc = 0; kc < 8; ++kc)
        #pragma unroll
        for (int mt = 0; mt < 2; ++mt) {
            int node = (kc < 4) ? nsrc[mt] : ndst[mt];
            a[mt][kc] = *(const bf16x8*)(h1h + (size_t)node * 128 + (kc & 3) * 32 + quad * 8);
        }

    // preload global tail B pairs 60..71
    bf16x8 bg[12];
    #pragma unroll
    for (int i = 0; i < 12; ++i)
        bg[i] = *(const bf16x8*)(w1h + (size_t)(60 + i) * 512 + lane * 8);

    // eattr -> bf16 fragments (chunk 8)
    bf16x8 a8[2];
    #pragma unroll
    for (int mt = 0; mt < 2; ++mt) {
        float fv[8] = {ef0[mt].x, ef0[mt].y, ef0[mt].z, ef0[mt].w,
                       ef1[mt].x, ef1[mt].y, ef1[mt].z, ef1[mt].w};
        #pragma unroll
        for (int j = 0; j < 8; ++j) a8[mt][j] = (short)f2bf(fv[j]);
    }

    __syncthreads();   // LDS B ready

    f32x4 acc[2][8] = {};

    #pragma unroll
    for (int p = 0; p < 72; ++p) {          // 9 chunks x 8 nt = 72 pairs (K=288)
        const int kc = p >> 3, nt = p & 7;
        bf16x8 bh = (p < 60) ? *(const bf16x8*)(&wlds[p * 512 + lane * 8]) : bg[p - 60];
        bf16x8 a0 = (kc < 8) ? a[0][kc] : a8[0];
        bf16x8 a1 = (kc < 8) ? a[1][kc] : a8[1];
        acc[0][nt] = __builtin_amdgcn_mfma_f32_16x16x32_bf16(a0, bh, acc[0][nt], 0, 0, 0);
        acc[1][nt] = __builtin_amdgcn_mfma_f32_16x16x32_bf16(a1, bh, acc[1][nt], 0, 0, 0);
    }

    float b1v[8], w2v[8];
    #pragma unroll
    for (int nt = 0; nt < 8; ++nt) {
        b1v[nt] = b1[nt * 16 + l15];
        w2v[nt] = W2[nt * 16 + l15];
    }
    const float b2s = b2[0];

    #pragma unroll
    for (int mt = 0; mt < 2; ++mt) {
        #pragma unroll
        for (int reg = 0; reg < 4; ++reg) {
            float s = 0.0f;
            #pragma unroll
            for (int nt = 0; nt < 8; ++nt) {
                float v = acc[mt][nt][reg] + b1v[nt];
                s += fmaxf(v, 0.0f) * w2v[nt];
            }
            s += __shfl_xor(s, 1);
            s += __shfl_xor(s, 2);
            s += __shfl_xor(s, 4);
            s += __shfl_xor(s, 8);
            if (l15 == 0) {
                int e = e0 + wave * 32 + mt * 16 + quad * 4 + reg;
                if (e < Ef) out[e] = s + b2s;
            }
        }
    }
}

extern "C" void kernel_launch(void* const* d_in, const int* in_sizes, int n_in,
                              void* d_out, int out_size, void* d_ws, size_t ws_size,
                              hipStream_t stream) {
    const float* x     = (const float*)d_in[0];
    const int*   ei    = (const int*)d_in[1];
    const int*   fei   = (const int*)d_in[2];
    const float* eattr = (const float*)d_in[3];
    const float* Wl0   = (const float*)d_in[4];
    const float* bl0   = (const float*)d_in[5];
    const float* Wr0   = (const float*)d_in[6];
    const float* Wl1   = (const float*)d_in[7];
    const float* bl1   = (const float*)d_in[8];
    const float* Wr1   = (const float*)d_in[9];
    const float* W1    = (const float*)d_in[10];
    const float* b1    = (const float*)d_in[11];
    const float* W2    = (const float*)d_in[12];
    const float* b2    = (const float*)d_in[13];

    const int E  = in_sizes[1] / 2;
    const int Ef = in_sizes[2] / 2;
    const int N  = in_sizes[0] / 64;

    const int* src  = ei;
    const int* dst  = ei + E;
    const int* fsrc = fei;
    const int* fdst = fei + Ef;

    // workspace layout (units: floats)
    float* wsf = (float*)d_ws;
    size_t o = 0;
    int* deg  = (int*)(wsf + o); o += 131072;
    int* off  = (int*)(wsf + o); o += 131072;
    int* pos  = (int*)(wsf + o); o += 131072;
    int* bsum = (int*)(wsf + o); o += 256;
    int* eid  = (int*)(wsf + o); o += 1 << 20;
    unsigned short* w0p = (unsigned short*)(wsf + o); o += 16384;
    unsigned short* wLp = (unsigned short*)(wsf + o); o += 32768;
    unsigned short* w1h = (unsigned short*)(wsf + o); o += 18432;
    unsigned short* xp  = (unsigned short*)(wsf + o); o += (size_t)N * 64;   // packed x; later h_hi
    unsigned short* xhi = (unsigned short*)(wsf + o); o += (size_t)N * 32;   // bf16-hi x rows
    unsigned short* aggp= (unsigned short*)(wsf + o); o += (size_t)N * 128;  // packed agg (both layers)
    unsigned short* h1_hi=(unsigned short*)(wsf + o); o += (size_t)N * 64;   // bf16-hi h1 rows

    unsigned short* h_hi = xp;   // overlay: mfma_layer0 writes its own block's rows only
    float* out = (float*)d_out;

    const int nb = (N + 1023) / 1024;

    hipMemsetAsync(deg, 0, (size_t)N * 4, stream);
    degree_kernel<<<(E + 255) / 256, 256, 0, stream>>>(dst, deg, E);
    scan_reduce<<<nb, 256, 0, stream>>>(deg, bsum, N);
    scan_bsum<<<1, 256, 0, stream>>>(bsum, nb);
    scan_final<<<nb, 256, 0, stream>>>(deg, bsum, off, pos, N, E);
    bucket_kernel<<<(E + 255) / 256, 256, 0, stream>>>(src, dst, pos, eid, E);

    pack_weights<<<(86016 + 255) / 256, 256, 0, stream>>>(Wl0, Wr0, Wl1, Wr1, W1, w0p, wLp, w1h);

    split_x<<<((N * 8) + 255) / 256, 256, 0, stream>>>(x, xp, xhi, N * 8);

    aggregate64p<<<(N + 3) / 4, 256, 0, stream>>>(xhi, eid, off, aggp, N);
    mfma_layer<64, 64, true, true><<<(N + 63) / 64, 256, 0, stream>>>(
        aggp, xp, w0p, bl0, h_hi, N);

    aggregate128p<<<(N + 3) / 4, 256, 0, stream>>>(h_hi, eid, off, aggp, N);
    mfma_layer<128, 128, false, false><<<(N + 63) / 64, 256, 0, stream>>>(
        aggp, h_hi, wLp, bl1, h1_hi, N);

    classify_mfma<<<(Ef + 127) / 128, 256, 0, stream>>>(
        h1_hi, fsrc, fdst, eattr, w1h, b1, W2, b2, out, Ef);
}